// Round 1
// baseline (238.043 us; speedup 1.0000x reference)
//
#include <hip/hip_runtime.h>
#include <math.h>

#define BB   4
#define NN   1024
#define HIDD 256
#define NHD  8
#define DHD  32
#define BHD  64           // bias-MLP hidden width
#define TI   4096         // table intervals over t in [-1, 1]
#define TP   4104         // table row stride (floats), per head

// ---------------- Kernel 1: bias-MLP lookup table (transposed: [NH][TP]) ----
__global__ __launch_bounds__(64) void table_kernel(
    const float* __restrict__ Wb1, const float* __restrict__ bb1,
    const float* __restrict__ Wb2, const float* __restrict__ bb2,
    const float* __restrict__ Wb3, const float* __restrict__ bb3,
    float* __restrict__ tbl)
{
  __shared__ float h1[BHD];
  __shared__ float h2[BHD];
  int j  = threadIdx.x;          // 0..63
  int pt = blockIdx.x;           // 0..TI
  float t = -1.0f + (float)pt * (2.0f / (float)TI);
  float z = fmaf(t, Wb1[j], bb1[j]);
  h1[j] = z / (1.0f + __expf(-z));            // silu
  __syncthreads();
  float acc = bb2[j];
  #pragma unroll 16
  for (int i = 0; i < BHD; ++i) acc = fmaf(h1[i], Wb2[i*BHD + j], acc);
  h2[j] = acc / (1.0f + __expf(-acc));        // silu
  __syncthreads();
  if (j < NHD) {
    float o = bb3[j];
    #pragma unroll 16
    for (int i = 0; i < BHD; ++i) o = fmaf(h2[i], Wb3[i*NHD + j], o);
    tbl[j*TP + pt] = o;
  }
}

// ---------------- Kernel 2: LayerNorm + QKV projection ----------------------
__global__ __launch_bounds__(256) void ln_qkv_kernel(
    const float* __restrict__ h, const float* __restrict__ W,
    const float* __restrict__ bqkv, const float* __restrict__ gamma,
    const float* __restrict__ beta,
    float* __restrict__ qws, float* __restrict__ kws, float* __restrict__ vws)
{
  __shared__ float xs[16][HIDD];
  int tid = threadIdx.x;
  int r = tid >> 4, l16 = tid & 15;
  int g = blockIdx.x * 16 + r;                 // flat row in [0, B*N)
  const float4* hrow = (const float4*)(h + (size_t)g * HIDD);
  float4 xv[4];
  float sum = 0.f, sq = 0.f;
  #pragma unroll
  for (int j = 0; j < 4; ++j) {
    xv[j] = hrow[l16*4 + j];
    sum += xv[j].x + xv[j].y + xv[j].z + xv[j].w;
    sq  += xv[j].x*xv[j].x + xv[j].y*xv[j].y + xv[j].z*xv[j].z + xv[j].w*xv[j].w;
  }
  #pragma unroll
  for (int off = 1; off < 16; off <<= 1) {
    sum += __shfl_xor(sum, off);
    sq  += __shfl_xor(sq,  off);
  }
  float mu  = sum * (1.0f/HIDD);
  float var = sq  * (1.0f/HIDD) - mu*mu;
  float rs  = rsqrtf(var + 1e-5f);
  #pragma unroll
  for (int j = 0; j < 4; ++j) {
    int k = l16*16 + j*4;
    float4 gv = *(const float4*)&gamma[k];
    float4 bv = *(const float4*)&beta[k];
    float4 o;
    o.x = fmaf((xv[j].x - mu)*rs, gv.x, bv.x);
    o.y = fmaf((xv[j].y - mu)*rs, gv.y, bv.y);
    o.z = fmaf((xv[j].z - mu)*rs, gv.z, bv.z);
    o.w = fmaf((xv[j].w - mu)*rs, gv.w, bv.w);
    *(float4*)&xs[r][k] = o;
  }
  __syncthreads();

  float acc[16][3];
  #pragma unroll
  for (int rr = 0; rr < 16; ++rr)
    #pragma unroll
    for (int cc = 0; cc < 3; ++cc) acc[rr][cc] = 0.f;

  for (int k4 = 0; k4 < HIDD/4; ++k4) {
    int k = k4 * 4;
    float w[3][4];
    #pragma unroll
    for (int cc = 0; cc < 3; ++cc) {
      int col = cc*256 + tid;
      #pragma unroll
      for (int j = 0; j < 4; ++j) w[cc][j] = W[(size_t)(k+j)*768 + col];
    }
    #pragma unroll
    for (int rr = 0; rr < 16; ++rr) {
      float4 x4 = *(const float4*)&xs[rr][k];   // broadcast read
      #pragma unroll
      for (int cc = 0; cc < 3; ++cc) {
        acc[rr][cc] = fmaf(x4.x, w[cc][0], acc[rr][cc]);
        acc[rr][cc] = fmaf(x4.y, w[cc][1], acc[rr][cc]);
        acc[rr][cc] = fmaf(x4.z, w[cc][2], acc[rr][cc]);
        acc[rr][cc] = fmaf(x4.w, w[cc][3], acc[rr][cc]);
      }
    }
  }
  #pragma unroll
  for (int cc = 0; cc < 3; ++cc) {
    int col = cc*256 + tid;
    float bq = bqkv[col];
    int head = (col & 255) >> 5;
    int d    = col & 31;
    float* dst = (cc == 0) ? qws : (cc == 1 ? kws : vws);
    #pragma unroll
    for (int rr = 0; rr < 16; ++rr) {
      int g2 = blockIdx.x*16 + rr;
      int b = g2 >> 10, n = g2 & 1023;
      dst[(((size_t)b*NHD + head)*NN + n)*DHD + d] = acc[rr][cc] + bq;
    }
  }
}

// ---------------- Kernel 3: flash attention + table bias --------------------
__global__ __launch_bounds__(256) void attn_kernel(
    const float* __restrict__ Q, const float* __restrict__ K,
    const float* __restrict__ V, const float* __restrict__ coord,
    const int* __restrict__ mask, const float* __restrict__ tbl,
    float* __restrict__ ao)
{
  __shared__ float tableL[TI + 1];
  __shared__ float Klds[64][36];   // +4 pad: quad k-stripe hits distinct banks
  __shared__ float Vlds[64][36];
  __shared__ float ckL[64];
  __shared__ int   mkL[64];
  int tid  = threadIdx.x;
  int bh   = blockIdx.y;           // 0..31
  int b    = bh >> 3;
  int head = bh & 7;
  int q0   = blockIdx.x * 64;
  for (int i = tid; i < TI + 1; i += 256) tableL[i] = tbl[head*TP + i];

  int sub = tid & 3;               // 4 lanes share one q row, k-striped
  int row = q0 + (tid >> 2);
  const float4* qrow = (const float4*)(Q + ((size_t)bh*NN + row)*DHD);
  float4 q4[8];
  #pragma unroll
  for (int i = 0; i < 8; ++i) q4[i] = qrow[i];
  float cq = coord[b*NN + row];
  float m = -INFINITY, lsum = 0.f;
  float4 a4[8];
  #pragma unroll
  for (int i = 0; i < 8; ++i) a4[i] = make_float4(0.f, 0.f, 0.f, 0.f);
  const float scale = 0.17677669529663689f;  // 1/sqrt(32)

  for (int kt = 0; kt < NN; kt += 64) {
    __syncthreads();
    #pragma unroll
    for (int jj = 0; jj < 2; ++jj) {
      int idx = tid + jj*256;                 // 0..511
      int rr = idx >> 3, c4 = idx & 7;
      const float4* kr = (const float4*)(K + ((size_t)bh*NN + kt + rr)*DHD);
      const float4* vr = (const float4*)(V + ((size_t)bh*NN + kt + rr)*DHD);
      *(float4*)&Klds[rr][c4*4] = kr[c4];
      *(float4*)&Vlds[rr][c4*4] = vr[c4];
    }
    if (tid < 64) {
      ckL[tid] = coord[b*NN + kt + tid];
      mkL[tid] = mask[b*NN + kt + tid];
    }
    __syncthreads();
    for (int it = 0; it < 16; ++it) {
      int kk = it*4 + sub;
      float4 kf[8];
      #pragma unroll
      for (int i = 0; i < 8; ++i) kf[i] = *(const float4*)&Klds[kk][i*4];
      float dot = 0.f;
      #pragma unroll
      for (int i = 0; i < 8; ++i) {
        dot = fmaf(q4[i].x, kf[i].x, dot);
        dot = fmaf(q4[i].y, kf[i].y, dot);
        dot = fmaf(q4[i].z, kf[i].z, dot);
        dot = fmaf(q4[i].w, kf[i].w, dot);
      }
      float tt = ckL[kk] - cq;
      float u  = (tt + 1.0f) * ((float)TI * 0.5f);
      u = fminf(fmaxf(u, 0.0f), (float)TI - 0.0005f);
      int   i0 = (int)u;
      float fr = u - (float)i0;
      float b0 = tableL[i0];
      float bias = fmaf(tableL[i0+1] - b0, fr, b0);
      float s = fmaf(dot, scale, bias);
      if (mkL[kk] != 0) {
        float4 vf[8];
        #pragma unroll
        for (int i = 0; i < 8; ++i) vf[i] = *(const float4*)&Vlds[kk][i*4];
        if (s <= m) {
          float p = __expf(s - m);
          lsum += p;
          #pragma unroll
          for (int i = 0; i < 8; ++i) {
            a4[i].x = fmaf(p, vf[i].x, a4[i].x);
            a4[i].y = fmaf(p, vf[i].y, a4[i].y);
            a4[i].z = fmaf(p, vf[i].z, a4[i].z);
            a4[i].w = fmaf(p, vf[i].w, a4[i].w);
          }
        } else {                               // rare: new running max
          float sc = __expf(m - s);
          lsum = fmaf(lsum, sc, 1.0f);
          #pragma unroll
          for (int i = 0; i < 8; ++i) {
            a4[i].x = fmaf(a4[i].x, sc, vf[i].x);
            a4[i].y = fmaf(a4[i].y, sc, vf[i].y);
            a4[i].z = fmaf(a4[i].z, sc, vf[i].z);
            a4[i].w = fmaf(a4[i].w, sc, vf[i].w);
          }
          m = s;
        }
      }
    }
  }
  // merge the 4 k-stripes of each q row (butterfly keeps all lanes valid)
  #pragma unroll
  for (int off = 1; off <= 2; off <<= 1) {
    float m2 = __shfl_xor(m, off);
    float l2 = __shfl_xor(lsum, off);
    float mn = fmaxf(m, m2);
    float sa = __expf(m  - mn);
    float sb = __expf(m2 - mn);
    lsum = lsum*sa + l2*sb;
    #pragma unroll
    for (int i = 0; i < 8; ++i) {
      float4 v = a4[i];
      float4 o;
      o.x = v.x*sa + __shfl_xor(v.x, off)*sb;
      o.y = v.y*sa + __shfl_xor(v.y, off)*sb;
      o.z = v.z*sa + __shfl_xor(v.z, off)*sb;
      o.w = v.w*sa + __shfl_xor(v.w, off)*sb;
      a4[i] = o;
    }
    m = mn;
  }
  float inv = 1.0f / lsum;
  float4 o0, o1;
  if (sub == 0)      { o0 = a4[0]; o1 = a4[1]; }
  else if (sub == 1) { o0 = a4[2]; o1 = a4[3]; }
  else if (sub == 2) { o0 = a4[4]; o1 = a4[5]; }
  else               { o0 = a4[6]; o1 = a4[7]; }
  o0.x *= inv; o0.y *= inv; o0.z *= inv; o0.w *= inv;
  o1.x *= inv; o1.y *= inv; o1.z *= inv; o1.w *= inv;
  float* dst = ao + ((size_t)b*NN + row)*HIDD + head*DHD + sub*8;
  *(float4*)dst     = o0;
  *(float4*)(dst+4) = o1;
}

// ---------------- Kernel 4: output projection + residual --------------------
__global__ __launch_bounds__(256) void proj_kernel(
    const float* __restrict__ ao, const float* __restrict__ h,
    const float* __restrict__ Wp, const float* __restrict__ bp,
    float* __restrict__ out)
{
  __shared__ float xs[16][HIDD];
  int tid = threadIdx.x;
  int n0 = blockIdx.x * 16;
  for (int v = tid; v < 16*64; v += 256) {
    int rr = v >> 6, c4 = v & 63;
    ((float4*)&xs[rr][0])[c4] = ((const float4*)(ao + (size_t)(n0+rr)*HIDD))[c4];
  }
  __syncthreads();
  float acc[16];
  #pragma unroll
  for (int rr = 0; rr < 16; ++rr) acc[rr] = 0.f;
  for (int k4 = 0; k4 < 64; ++k4) {
    int k = k4*4;
    float w0 = Wp[(size_t)(k+0)*HIDD + tid];
    float w1 = Wp[(size_t)(k+1)*HIDD + tid];
    float w2 = Wp[(size_t)(k+2)*HIDD + tid];
    float w3 = Wp[(size_t)(k+3)*HIDD + tid];
    #pragma unroll
    for (int rr = 0; rr < 16; ++rr) {
      float4 x4 = *(const float4*)&xs[rr][k];   // broadcast read
      acc[rr] = fmaf(x4.x, w0, acc[rr]);
      acc[rr] = fmaf(x4.y, w1, acc[rr]);
      acc[rr] = fmaf(x4.z, w2, acc[rr]);
      acc[rr] = fmaf(x4.w, w3, acc[rr]);
    }
  }
  float bpv = bp[tid];
  #pragma unroll
  for (int rr = 0; rr < 16; ++rr) {
    size_t o = (size_t)(n0 + rr)*HIDD + tid;
    out[o] = h[o] + acc[rr] + bpv;
  }
}

// ---------------- launch ----------------------------------------------------
extern "C" void kernel_launch(void* const* d_in, const int* in_sizes, int n_in,
                              void* d_out, int out_size, void* d_ws, size_t ws_size,
                              hipStream_t stream)
{
  const float* h     = (const float*)d_in[0];
  const float* coord = (const float*)d_in[1];
  const int*   mask  = (const int*)  d_in[2];
  const float* Wqkv  = (const float*)d_in[3];
  const float* bqkv  = (const float*)d_in[4];
  const float* Wproj = (const float*)d_in[5];
  const float* bproj = (const float*)d_in[6];
  const float* gamma = (const float*)d_in[7];
  const float* beta  = (const float*)d_in[8];
  const float* Wb1   = (const float*)d_in[9];
  const float* bb1   = (const float*)d_in[10];
  const float* Wb2   = (const float*)d_in[11];
  const float* bb2   = (const float*)d_in[12];
  const float* Wb3   = (const float*)d_in[13];
  const float* bb3   = (const float*)d_in[14];
  float* out = (float*)d_out;

  float* ws  = (float*)d_ws;
  float* tbl = ws;                                  // 8*4104   = 32832 floats
  float* qws = ws + 32832;                          // 1048576 floats each
  float* kws = qws + (size_t)BB*NHD*NN*DHD;
  float* vws = kws + (size_t)BB*NHD*NN*DHD;
  float* ao  = vws + (size_t)BB*NHD*NN*DHD;

  table_kernel<<<dim3(TI + 1), dim3(64), 0, stream>>>(Wb1, bb1, Wb2, bb2, Wb3, bb3, tbl);
  ln_qkv_kernel<<<dim3(BB*NN/16), dim3(256), 0, stream>>>(h, Wqkv, bqkv, gamma, beta, qws, kws, vws);
  attn_kernel<<<dim3(NN/64, BB*NHD), dim3(256), 0, stream>>>(qws, kws, vws, coord, mask, tbl, ao);
  proj_kernel<<<dim3(BB*NN/16), dim3(256), 0, stream>>>(ao, h, Wproj, bproj, out);
}

// Round 2
// 148.421 us; speedup vs baseline: 1.6038x; 1.6038x over previous
//
#include <hip/hip_runtime.h>
#include <math.h>

#define BB   4
#define NN   1024
#define HIDD 256
#define NHD  8
#define DHD  32
#define BHD  64
#define TI2  2048          // table intervals over t in [-1,1]

typedef __attribute__((ext_vector_type(8))) short bf16x8;
typedef __attribute__((ext_vector_type(4))) float f32x4;

__device__ __forceinline__ unsigned short f2bf(float x) {
  union { float f; unsigned u; } c; c.f = x;
  unsigned r = c.u + 0x7FFFu + ((c.u >> 16) & 1u);
  return (unsigned short)(r >> 16);
}

// ---------------- Kernel 1a: bias-MLP point values tmp[NH][TI2+1] -----------
__global__ __launch_bounds__(64) void table_kernel(
    const float* __restrict__ Wb1, const float* __restrict__ bb1,
    const float* __restrict__ Wb2, const float* __restrict__ bb2,
    const float* __restrict__ Wb3, const float* __restrict__ bb3,
    float* __restrict__ tmp)
{
  __shared__ float h1[BHD];
  __shared__ float h2[BHD];
  int j  = threadIdx.x;
  int pt = blockIdx.x;                          // 0..TI2
  float t = -1.0f + (float)pt * (2.0f / (float)TI2);
  float z = fmaf(t, Wb1[j], bb1[j]);
  h1[j] = z / (1.0f + __expf(-z));
  __syncthreads();
  float acc = bb2[j];
  #pragma unroll 16
  for (int i = 0; i < BHD; ++i) acc = fmaf(h1[i], Wb2[i*BHD + j], acc);
  h2[j] = acc / (1.0f + __expf(-acc));
  __syncthreads();
  if (j < NHD) {
    float o = bb3[j];
    #pragma unroll 16
    for (int i = 0; i < BHD; ++i) o = fmaf(h2[i], Wb3[i*NHD + j], o);
    tmp[j*(TI2+1) + pt] = o;
  }
}

// ---------------- Kernel 1b: pack {base, slope} float2 ----------------------
__global__ __launch_bounds__(256) void tbl_pack_kernel(
    const float* __restrict__ tmp, float2* __restrict__ tbl2)
{
  int idx  = blockIdx.x * 256 + threadIdx.x;    // 0..8*2048-1
  int head = idx >> 11;
  int i    = idx & 2047;
  float b = tmp[head*(TI2+1) + i];
  float n = tmp[head*(TI2+1) + i + 1];
  tbl2[head*TI2 + i] = make_float2(b, n - b);
}

// ---------------- Kernel 2: LayerNorm + QKV (bf16 out, V transposed) --------
__global__ __launch_bounds__(256) void ln_qkv_kernel(
    const float* __restrict__ h, const float* __restrict__ W,
    const float* __restrict__ bqkv, const float* __restrict__ gamma,
    const float* __restrict__ beta,
    unsigned short* __restrict__ qws, unsigned short* __restrict__ kws,
    unsigned short* __restrict__ vtws)
{
  __shared__ float xs[8][HIDD];
  int tid = threadIdx.x;
  int r = tid >> 5, l32 = tid & 31;
  int g = blockIdx.x * 8 + r;                    // flat row in [0, B*N)
  const float4* hrow = (const float4*)(h + (size_t)g * HIDD);
  float4 xv[2];
  float sum = 0.f, sq = 0.f;
  #pragma unroll
  for (int j = 0; j < 2; ++j) {
    xv[j] = hrow[l32*2 + j];
    sum += xv[j].x + xv[j].y + xv[j].z + xv[j].w;
    sq  += xv[j].x*xv[j].x + xv[j].y*xv[j].y + xv[j].z*xv[j].z + xv[j].w*xv[j].w;
  }
  #pragma unroll
  for (int off = 1; off < 32; off <<= 1) {
    sum += __shfl_xor(sum, off);
    sq  += __shfl_xor(sq,  off);
  }
  float mu  = sum * (1.0f/HIDD);
  float var = sq  * (1.0f/HIDD) - mu*mu;
  float rs  = rsqrtf(var + 1e-5f);
  #pragma unroll
  for (int j = 0; j < 2; ++j) {
    int k = l32*8 + j*4;
    float4 gv = *(const float4*)&gamma[k];
    float4 bv = *(const float4*)&beta[k];
    float4 o;
    o.x = fmaf((xv[j].x - mu)*rs, gv.x, bv.x);
    o.y = fmaf((xv[j].y - mu)*rs, gv.y, bv.y);
    o.z = fmaf((xv[j].z - mu)*rs, gv.z, bv.z);
    o.w = fmaf((xv[j].w - mu)*rs, gv.w, bv.w);
    *(float4*)&xs[r][k] = o;
  }
  __syncthreads();

  float acc[8][3];
  #pragma unroll
  for (int rr = 0; rr < 8; ++rr)
    #pragma unroll
    for (int cc = 0; cc < 3; ++cc) acc[rr][cc] = 0.f;

  for (int k4 = 0; k4 < HIDD/4; ++k4) {
    int k = k4 * 4;
    float w[3][4];
    #pragma unroll
    for (int cc = 0; cc < 3; ++cc) {
      int col = cc*256 + tid;
      #pragma unroll
      for (int j = 0; j < 4; ++j) w[cc][j] = W[(size_t)(k+j)*768 + col];
    }
    #pragma unroll
    for (int rr = 0; rr < 8; ++rr) {
      float4 x4 = *(const float4*)&xs[rr][k];
      #pragma unroll
      for (int cc = 0; cc < 3; ++cc) {
        acc[rr][cc] = fmaf(x4.x, w[cc][0], acc[rr][cc]);
        acc[rr][cc] = fmaf(x4.y, w[cc][1], acc[rr][cc]);
        acc[rr][cc] = fmaf(x4.z, w[cc][2], acc[rr][cc]);
        acc[rr][cc] = fmaf(x4.w, w[cc][3], acc[rr][cc]);
      }
    }
  }
  int head = tid >> 5, d = tid & 31;
  float bq0 = bqkv[tid], bq1 = bqkv[256 + tid], bq2 = bqkv[512 + tid];
  #pragma unroll
  for (int rr = 0; rr < 8; ++rr) {
    int g2 = blockIdx.x*8 + rr;
    int b = g2 >> 10, n = g2 & 1023;
    size_t bhn = ((size_t)(b*NHD + head)*NN + n)*DHD + d;
    qws[bhn] = f2bf(acc[rr][0] + bq0);
    kws[bhn] = f2bf(acc[rr][1] + bq1);
    vtws[((size_t)(b*NHD + head)*DHD + d)*NN + n] = f2bf(acc[rr][2] + bq2);
  }
}

// ---------------- Kernel 3: MFMA flash attention + table bias ---------------
__global__ __launch_bounds__(256) void attn_kernel(
    const unsigned short* __restrict__ Q, const unsigned short* __restrict__ K,
    const unsigned short* __restrict__ Vt, const float* __restrict__ coord,
    const int* __restrict__ mask, const float2* __restrict__ tbl2,
    float* __restrict__ ao)
{
  __shared__ float2 tableL[TI2];                  // 16384 B
  __shared__ unsigned short Klds[64][40];         //  5120 B (pad 8)
  __shared__ unsigned short Vtlds[32][72];        //  4608 B (pad 8)
  __shared__ float2 ckpen[64];                    //   512 B
  __shared__ unsigned short Plds[4][16][72];      //  9216 B (per-wave)

  int tid = threadIdx.x;
  int lane = tid & 63;
  int w = tid >> 6;
  int bh = blockIdx.y;
  int b = bh >> 3, head = bh & 7;
  int qbase = blockIdx.x * 64 + w * 16;
  int lo = lane & 15, hi = lane >> 4;

  // per-head slope table → LDS (1024 float4)
  {
    const float4* src = (const float4*)tbl2;
    float4* dst = (float4*)tableL;
    for (int i = tid; i < TI2/2; i += 256) dst[i] = src[head*(TI2/2) + i];
  }

  // Q fragment: lane holds Q[qbase+lo][hi*8 .. +8]
  bf16x8 qf = *(const bf16x8*)&Q[((size_t)bh*NN + qbase + lo)*DHD + hi*8];
  float4 cq4 = *(const float4*)&coord[b*NN + qbase + hi*4];
  float cq[4] = {cq4.x, cq4.y, cq4.z, cq4.w};

  float mrun[4], lrun[4];
  f32x4 oacc[2];
  #pragma unroll
  for (int r = 0; r < 4; ++r) { mrun[r] = -1e30f; lrun[r] = 0.f; }
  oacc[0] = (f32x4){0.f,0.f,0.f,0.f};
  oacc[1] = (f32x4){0.f,0.f,0.f,0.f};
  const float scale = 0.17677669529663689f;       // 1/sqrt(32)

  for (int kt = 0; kt < NN; kt += 64) {
    __syncthreads();                               // prev tile fully consumed
    {
      int r = tid >> 2, s = tid & 3;               // K tile: 64 rows x 32
      bf16x8 kv = *(const bf16x8*)&K[((size_t)bh*NN + kt + r)*DHD + s*8];
      *(bf16x8*)&Klds[r][s*8] = kv;
      int r2 = tid >> 3, s2 = tid & 7;             // Vt tile: 32 rows x 64
      bf16x8 vv = *(const bf16x8*)&Vt[((size_t)bh*DHD + r2)*NN + kt + s2*8];
      *(bf16x8*)&Vtlds[r2][s2*8] = vv;
      if (tid < 64) {
        float ck = coord[b*NN + kt + tid];
        int mk = mask[b*NN + kt + tid];
        ckpen[tid] = make_float2(ck, mk ? 0.0f : -1e31f);
      }
    }
    __syncthreads();

    // S = Q·K^T  (4 n-subtiles of 16)
    f32x4 z = {0.f,0.f,0.f,0.f};
    f32x4 sacc[4];
    #pragma unroll
    for (int nt = 0; nt < 4; ++nt) {
      bf16x8 kf = *(const bf16x8*)&Klds[nt*16 + lo][hi*8];
      sacc[nt] = __builtin_amdgcn_mfma_f32_16x16x32_bf16(qf, kf, z, 0, 0, 0);
    }

    // bias via slope table + mask penalty
    float sv[4][4];
    #pragma unroll
    for (int nt = 0; nt < 4; ++nt) {
      float2 cp = ckpen[nt*16 + lo];
      #pragma unroll
      for (int r = 0; r < 4; ++r) {
        float tt = cp.x - cq[r];
        float u  = fmaf(tt, (float)TI2*0.5f, (float)TI2*0.5f);
        u = fminf(fmaxf(u, 0.0f), (float)TI2 - 0.01f);
        int   i0 = (int)u;
        float fr = u - (float)i0;
        float2 e = tableL[i0];
        sv[nt][r] = fmaf(sacc[nt][r], scale, fmaf(e.y, fr, e.x) + cp.y);
      }
    }

    // online softmax (row = q = hi*4+r, cols spread over 16-lane group)
    #pragma unroll
    for (int r = 0; r < 4; ++r) {
      float pm = fmaxf(fmaxf(sv[0][r], sv[1][r]), fmaxf(sv[2][r], sv[3][r]));
      pm = fmaxf(pm, __shfl_xor(pm, 1));
      pm = fmaxf(pm, __shfl_xor(pm, 2));
      pm = fmaxf(pm, __shfl_xor(pm, 4));
      pm = fmaxf(pm, __shfl_xor(pm, 8));
      float mn = fmaxf(mrun[r], pm);
      float sf = __expf(mrun[r] - mn);
      mrun[r] = mn;
      lrun[r] *= sf;
      oacc[0][r] *= sf;
      oacc[1][r] *= sf;
      float ps = 0.f;
      #pragma unroll
      for (int nt = 0; nt < 4; ++nt) {
        float p = __expf(sv[nt][r] - mn);
        ps += p;
        Plds[w][hi*4 + r][nt*16 + lo] = f2bf(p);   // D-layout → A-layout via LDS
      }
      lrun[r] += ps;
    }
    __syncthreads();                               // P visible wave-wide

    // O += P·V  (A = P from Plds, B = V from Vt; 2 k-steps, 2 d-subtiles)
    #pragma unroll
    for (int ks = 0; ks < 2; ++ks) {
      bf16x8 pf = *(const bf16x8*)&Plds[w][lo][ks*32 + hi*8];
      #pragma unroll
      for (int n2 = 0; n2 < 2; ++n2) {
        bf16x8 vf = *(const bf16x8*)&Vtlds[n2*16 + lo][ks*32 + hi*8];
        oacc[n2] = __builtin_amdgcn_mfma_f32_16x16x32_bf16(pf, vf, oacc[n2], 0, 0, 0);
      }
    }
  }

  // epilogue: reduce row sums across the 16-lane group, normalize, store
  #pragma unroll
  for (int r = 0; r < 4; ++r) {
    float t = lrun[r];
    t += __shfl_xor(t, 1);
    t += __shfl_xor(t, 2);
    t += __shfl_xor(t, 4);
    t += __shfl_xor(t, 8);
    float inv = 1.0f / t;
    #pragma unroll
    for (int n2 = 0; n2 < 2; ++n2) {
      ao[((size_t)(b*NN + qbase + hi*4 + r))*HIDD + head*DHD + n2*16 + lo]
          = oacc[n2][r] * inv;
    }
  }
}

// ---------------- Kernel 4: output projection + residual --------------------
__global__ __launch_bounds__(256) void proj_kernel(
    const float* __restrict__ ao, const float* __restrict__ h,
    const float* __restrict__ Wp, const float* __restrict__ bp,
    float* __restrict__ out)
{
  __shared__ float xs[8][HIDD];
  int tid = threadIdx.x;
  int n0 = blockIdx.x * 8;
  for (int v = tid; v < 8*64; v += 256) {
    int rr = v >> 6, c4 = v & 63;
    ((float4*)&xs[rr][0])[c4] = ((const float4*)(ao + (size_t)(n0+rr)*HIDD))[c4];
  }
  __syncthreads();
  float acc[8];
  #pragma unroll
  for (int rr = 0; rr < 8; ++rr) acc[rr] = 0.f;
  for (int k4 = 0; k4 < 64; ++k4) {
    int k = k4*4;
    float w0 = Wp[(size_t)(k+0)*HIDD + tid];
    float w1 = Wp[(size_t)(k+1)*HIDD + tid];
    float w2 = Wp[(size_t)(k+2)*HIDD + tid];
    float w3 = Wp[(size_t)(k+3)*HIDD + tid];
    #pragma unroll
    for (int rr = 0; rr < 8; ++rr) {
      float4 x4 = *(const float4*)&xs[rr][k];
      acc[rr] = fmaf(x4.x, w0, acc[rr]);
      acc[rr] = fmaf(x4.y, w1, acc[rr]);
      acc[rr] = fmaf(x4.z, w2, acc[rr]);
      acc[rr] = fmaf(x4.w, w3, acc[rr]);
    }
  }
  float bpv = bp[tid];
  #pragma unroll
  for (int rr = 0; rr < 8; ++rr) {
    size_t o = (size_t)(n0 + rr)*HIDD + tid;
    out[o] = h[o] + acc[rr] + bpv;
  }
}

// ---------------- launch ----------------------------------------------------
extern "C" void kernel_launch(void* const* d_in, const int* in_sizes, int n_in,
                              void* d_out, int out_size, void* d_ws, size_t ws_size,
                              hipStream_t stream)
{
  const float* h     = (const float*)d_in[0];
  const float* coord = (const float*)d_in[1];
  const int*   mask  = (const int*)  d_in[2];
  const float* Wqkv  = (const float*)d_in[3];
  const float* bqkv  = (const float*)d_in[4];
  const float* Wproj = (const float*)d_in[5];
  const float* bproj = (const float*)d_in[6];
  const float* gamma = (const float*)d_in[7];
  const float* beta  = (const float*)d_in[8];
  const float* Wb1   = (const float*)d_in[9];
  const float* bb1   = (const float*)d_in[10];
  const float* Wb2   = (const float*)d_in[11];
  const float* bb2   = (const float*)d_in[12];
  const float* Wb3   = (const float*)d_in[13];
  const float* bb3   = (const float*)d_in[14];
  float* out = (float*)d_out;

  float* ws = (float*)d_ws;
  float*  tmp  = ws;                               // 8*2049 = 16392 → pad 16400
  float2* tbl2 = (float2*)(ws + 16400);            // 8*2048 float2 = 32768 floats
  unsigned short* qws  = (unsigned short*)(ws + 49168);
  unsigned short* kws  = qws + (size_t)BB*NHD*NN*DHD;   // 1048576 ushorts each
  unsigned short* vtws = kws + (size_t)BB*NHD*NN*DHD;
  float* ao = (float*)(vtws + (size_t)BB*NHD*NN*DHD);   // 1048576 floats

  table_kernel<<<dim3(TI2 + 1), dim3(64), 0, stream>>>(Wb1, bb1, Wb2, bb2, Wb3, bb3, tmp);
  tbl_pack_kernel<<<dim3(64), dim3(256), 0, stream>>>(tmp, tbl2);
  ln_qkv_kernel<<<dim3(BB*NN/8), dim3(256), 0, stream>>>(h, Wqkv, bqkv, gamma, beta, qws, kws, vtws);
  attn_kernel<<<dim3(NN/64, BB*NHD), dim3(256), 0, stream>>>(qws, kws, vtws, coord, mask, tbl2, ao);
  proj_kernel<<<dim3(BB*NN/8), dim3(256), 0, stream>>>(ao, h, Wproj, bproj, out);
}

// Round 3
// 88.888 us; speedup vs baseline: 2.6780x; 1.6698x over previous
//
#include <hip/hip_runtime.h>
#include <math.h>

#define BB   4
#define NN   1024
#define HIDD 256
#define NHD  8
#define DHD  32
#define BHD  64
#define TI2  2048          // table intervals over t in [-1,1]

typedef __attribute__((ext_vector_type(8))) short bf16x8;
typedef __attribute__((ext_vector_type(4))) float f32x4;

__device__ __forceinline__ unsigned short f2bf(float x) {
  union { float f; unsigned u; } c; c.f = x;
  unsigned r = c.u + 0x7FFFu + ((c.u >> 16) & 1u);
  return (unsigned short)(r >> 16);
}

// ---------------- Kernel 1a: bias-MLP point values tmp[NH][TI2+1] -----------
__global__ __launch_bounds__(64) void table_kernel(
    const float* __restrict__ Wb1, const float* __restrict__ bb1,
    const float* __restrict__ Wb2, const float* __restrict__ bb2,
    const float* __restrict__ Wb3, const float* __restrict__ bb3,
    float* __restrict__ tmp)
{
  __shared__ float h1[BHD];
  __shared__ float h2[BHD];
  int j  = threadIdx.x;
  int pt = blockIdx.x;                          // 0..TI2
  float t = -1.0f + (float)pt * (2.0f / (float)TI2);
  float z = fmaf(t, Wb1[j], bb1[j]);
  h1[j] = z / (1.0f + __expf(-z));
  __syncthreads();
  float acc = bb2[j];
  #pragma unroll 16
  for (int i = 0; i < BHD; ++i) acc = fmaf(h1[i], Wb2[i*BHD + j], acc);
  h2[j] = acc / (1.0f + __expf(-acc));
  __syncthreads();
  if (j < NHD) {
    float o = bb3[j];
    #pragma unroll 16
    for (int i = 0; i < BHD; ++i) o = fmaf(h2[i], Wb3[i*NHD + j], o);
    tmp[j*(TI2+1) + pt] = o;
  }
}

// ---------------- Kernel 1b: pack {base, slope} float2 ----------------------
__global__ __launch_bounds__(256) void tbl_pack_kernel(
    const float* __restrict__ tmp, float2* __restrict__ tbl2)
{
  int idx  = blockIdx.x * 256 + threadIdx.x;    // 0..8*2048-1
  int head = idx >> 11;
  int i    = idx & 2047;
  float b = tmp[head*(TI2+1) + i];
  float n = tmp[head*(TI2+1) + i + 1];
  tbl2[head*TI2 + i] = make_float2(b, n - b);
}

// ---------------- Kernel 1c: weight transpose+convert W[k][n] -> Wt[n][k] ---
__global__ __launch_bounds__(256) void wt_kernel(
    const float* __restrict__ W, unsigned short* __restrict__ Wt, int ncols)
{
  __shared__ float t[16][17];
  int sx = threadIdx.x & 15, sy = threadIdx.x >> 4;
  int n0 = blockIdx.x * 16, k0 = blockIdx.y * 16;
  t[sy][sx] = W[(size_t)(k0 + sy) * ncols + n0 + sx];
  __syncthreads();
  Wt[(size_t)(n0 + sy) * 256 + k0 + sx] = f2bf(t[sx][sy]);
}

// ---------------- Kernel 2a: LayerNorm -> xln bf16 [4096][256] --------------
__global__ __launch_bounds__(256) void ln_kernel(
    const float* __restrict__ h, const float* __restrict__ gamma,
    const float* __restrict__ beta, unsigned short* __restrict__ xln)
{
  int tid = threadIdx.x;
  int r = tid >> 5, l32 = tid & 31;
  int g = blockIdx.x * 8 + r;                    // flat row in [0, B*N)
  const float4* hrow = (const float4*)(h + (size_t)g * HIDD);
  float4 xv[2];
  float sum = 0.f, sq = 0.f;
  #pragma unroll
  for (int j = 0; j < 2; ++j) {
    xv[j] = hrow[l32*2 + j];
    sum += xv[j].x + xv[j].y + xv[j].z + xv[j].w;
    sq  += xv[j].x*xv[j].x + xv[j].y*xv[j].y + xv[j].z*xv[j].z + xv[j].w*xv[j].w;
  }
  #pragma unroll
  for (int off = 1; off < 32; off <<= 1) {
    sum += __shfl_xor(sum, off);
    sq  += __shfl_xor(sq,  off);
  }
  float mu  = sum * (1.0f/HIDD);
  float var = sq  * (1.0f/HIDD) - mu*mu;
  float rs  = rsqrtf(var + 1e-5f);
  union { bf16x8 v; unsigned short u[8]; } o;
  #pragma unroll
  for (int j = 0; j < 2; ++j) {
    int k = l32*8 + j*4;
    float4 gv = *(const float4*)&gamma[k];
    float4 bv = *(const float4*)&beta[k];
    o.u[j*4+0] = f2bf(fmaf((xv[j].x - mu)*rs, gv.x, bv.x));
    o.u[j*4+1] = f2bf(fmaf((xv[j].y - mu)*rs, gv.y, bv.y));
    o.u[j*4+2] = f2bf(fmaf((xv[j].z - mu)*rs, gv.z, bv.z));
    o.u[j*4+3] = f2bf(fmaf((xv[j].w - mu)*rs, gv.w, bv.w));
  }
  *(bf16x8*)&xln[(size_t)g*HIDD + l32*8] = o.v;
}

// ---------------- Kernel 2b: MFMA QKV GEMM [4096x256]x[256x768] -------------
__global__ __launch_bounds__(256) void qkv_mm_kernel(
    const unsigned short* __restrict__ X, const unsigned short* __restrict__ Wt,
    const float* __restrict__ bqkv,
    unsigned short* __restrict__ qws, unsigned short* __restrict__ kws,
    unsigned short* __restrict__ vtws)
{
  int tid = threadIdx.x, lane = tid & 63, w = tid >> 6;
  int lo = lane & 15, hi = lane >> 4;
  int m0 = blockIdx.x * 64 + w * 16;             // wave's 16 rows
  int n0 = blockIdx.y * 128;
  f32x4 acc[8];
  #pragma unroll
  for (int nt = 0; nt < 8; ++nt) acc[nt] = (f32x4){0.f,0.f,0.f,0.f};

  for (int ks = 0; ks < 8; ++ks) {
    bf16x8 af = *(const bf16x8*)&X[(size_t)(m0 + lo)*256 + ks*32 + hi*8];
    #pragma unroll
    for (int nt = 0; nt < 8; ++nt) {
      bf16x8 bf = *(const bf16x8*)&Wt[(size_t)(n0 + nt*16 + lo)*256 + ks*32 + hi*8];
      acc[nt] = __builtin_amdgcn_mfma_f32_16x16x32_bf16(af, bf, acc[nt], 0, 0, 0);
    }
  }

  int b = m0 >> 10;
  int nbase = (m0 & 1023) + hi*4;
  #pragma unroll
  for (int nt = 0; nt < 8; ++nt) {
    int c = n0 + nt*16 + lo;
    int cc = c >> 8;                              // uniform per (block, nt)
    int cr = c & 255;
    int head = cr >> 5, d = cr & 31;
    float bq = bqkv[c];
    size_t bh = (size_t)(b*NHD + head);
    #pragma unroll
    for (int r = 0; r < 4; ++r) {
      unsigned short val = f2bf(acc[nt][r] + bq);
      int nl = nbase + r;
      if (cc == 0)      qws[(bh*NN + nl)*DHD + d] = val;
      else if (cc == 1) kws[(bh*NN + nl)*DHD + d] = val;
      else              vtws[(bh*DHD + d)*NN + nl] = val;
    }
  }
}

// ---------------- Kernel 3: MFMA flash attention + table bias ---------------
__global__ __launch_bounds__(256) void attn_kernel(
    const unsigned short* __restrict__ Q, const unsigned short* __restrict__ K,
    const unsigned short* __restrict__ Vt, const float* __restrict__ coord,
    const int* __restrict__ mask, const float2* __restrict__ tbl2,
    unsigned short* __restrict__ ao)
{
  __shared__ float2 tableL[TI2];                  // 16384 B
  __shared__ unsigned short Klds[64][40];
  __shared__ unsigned short Vtlds[32][72];
  __shared__ float2 ckpen[64];
  __shared__ unsigned short Plds[4][16][72];

  int tid = threadIdx.x;
  int lane = tid & 63;
  int w = tid >> 6;
  int bh = blockIdx.y;
  int b = bh >> 3, head = bh & 7;
  int qbase = blockIdx.x * 64 + w * 16;
  int lo = lane & 15, hi = lane >> 4;

  {
    const float4* src = (const float4*)tbl2;
    float4* dst = (float4*)tableL;
    for (int i = tid; i < TI2/2; i += 256) dst[i] = src[head*(TI2/2) + i];
  }

  bf16x8 qf = *(const bf16x8*)&Q[((size_t)bh*NN + qbase + lo)*DHD + hi*8];
  float4 cq4 = *(const float4*)&coord[b*NN + qbase + hi*4];
  float cq[4] = {cq4.x, cq4.y, cq4.z, cq4.w};

  float mrun[4], lrun[4];
  f32x4 oacc[2];
  #pragma unroll
  for (int r = 0; r < 4; ++r) { mrun[r] = -1e30f; lrun[r] = 0.f; }
  oacc[0] = (f32x4){0.f,0.f,0.f,0.f};
  oacc[1] = (f32x4){0.f,0.f,0.f,0.f};
  const float scale = 0.17677669529663689f;       // 1/sqrt(32)

  for (int kt = 0; kt < NN; kt += 64) {
    __syncthreads();
    {
      int r = tid >> 2, s = tid & 3;
      bf16x8 kv = *(const bf16x8*)&K[((size_t)bh*NN + kt + r)*DHD + s*8];
      *(bf16x8*)&Klds[r][s*8] = kv;
      int r2 = tid >> 3, s2 = tid & 7;
      bf16x8 vv = *(const bf16x8*)&Vt[((size_t)bh*DHD + r2)*NN + kt + s2*8];
      *(bf16x8*)&Vtlds[r2][s2*8] = vv;
      if (tid < 64) {
        float ck = coord[b*NN + kt + tid];
        int mk = mask[b*NN + kt + tid];
        ckpen[tid] = make_float2(ck, mk ? 0.0f : -1e31f);
      }
    }
    __syncthreads();

    f32x4 z = {0.f,0.f,0.f,0.f};
    f32x4 sacc[4];
    #pragma unroll
    for (int nt = 0; nt < 4; ++nt) {
      bf16x8 kf = *(const bf16x8*)&Klds[nt*16 + lo][hi*8];
      sacc[nt] = __builtin_amdgcn_mfma_f32_16x16x32_bf16(qf, kf, z, 0, 0, 0);
    }

    float sv[4][4];
    #pragma unroll
    for (int nt = 0; nt < 4; ++nt) {
      float2 cp = ckpen[nt*16 + lo];
      #pragma unroll
      for (int r = 0; r < 4; ++r) {
        float tt = cp.x - cq[r];
        float u  = fmaf(tt, (float)TI2*0.5f, (float)TI2*0.5f);
        u = fminf(fmaxf(u, 0.0f), (float)TI2 - 0.01f);
        int   i0 = (int)u;
        float fr = u - (float)i0;
        float2 e = tableL[i0];
        sv[nt][r] = fmaf(sacc[nt][r], scale, fmaf(e.y, fr, e.x) + cp.y);
      }
    }

    #pragma unroll
    for (int r = 0; r < 4; ++r) {
      float pm = fmaxf(fmaxf(sv[0][r], sv[1][r]), fmaxf(sv[2][r], sv[3][r]));
      pm = fmaxf(pm, __shfl_xor(pm, 1));
      pm = fmaxf(pm, __shfl_xor(pm, 2));
      pm = fmaxf(pm, __shfl_xor(pm, 4));
      pm = fmaxf(pm, __shfl_xor(pm, 8));
      float mn = fmaxf(mrun[r], pm);
      float sf = __expf(mrun[r] - mn);
      mrun[r] = mn;
      lrun[r] *= sf;
      oacc[0][r] *= sf;
      oacc[1][r] *= sf;
      float ps = 0.f;
      #pragma unroll
      for (int nt = 0; nt < 4; ++nt) {
        float p = __expf(sv[nt][r] - mn);
        ps += p;
        Plds[w][hi*4 + r][nt*16 + lo] = f2bf(p);
      }
      lrun[r] += ps;
    }
    __syncthreads();

    #pragma unroll
    for (int ks = 0; ks < 2; ++ks) {
      bf16x8 pf = *(const bf16x8*)&Plds[w][lo][ks*32 + hi*8];
      #pragma unroll
      for (int n2 = 0; n2 < 2; ++n2) {
        bf16x8 vf = *(const bf16x8*)&Vtlds[n2*16 + lo][ks*32 + hi*8];
        oacc[n2] = __builtin_amdgcn_mfma_f32_16x16x32_bf16(pf, vf, oacc[n2], 0, 0, 0);
      }
    }
  }

  #pragma unroll
  for (int r = 0; r < 4; ++r) {
    float t = lrun[r];
    t += __shfl_xor(t, 1);
    t += __shfl_xor(t, 2);
    t += __shfl_xor(t, 4);
    t += __shfl_xor(t, 8);
    float inv = 1.0f / t;
    #pragma unroll
    for (int n2 = 0; n2 < 2; ++n2) {
      ao[((size_t)(b*NN + qbase + hi*4 + r))*HIDD + head*DHD + n2*16 + lo]
          = f2bf(oacc[n2][r] * inv);
    }
  }
}

// ---------------- Kernel 4: MFMA proj GEMM + bias + residual ----------------
__global__ __launch_bounds__(256) void proj_mm_kernel(
    const unsigned short* __restrict__ AO, const unsigned short* __restrict__ Wpt,
    const float* __restrict__ bp, const float* __restrict__ h,
    float* __restrict__ out)
{
  int tid = threadIdx.x, lane = tid & 63, w = tid >> 6;
  int lo = lane & 15, hi = lane >> 4;
  int m0 = blockIdx.x * 64 + w * 16;
  int n0 = blockIdx.y * 64;
  f32x4 acc[4];
  #pragma unroll
  for (int nt = 0; nt < 4; ++nt) acc[nt] = (f32x4){0.f,0.f,0.f,0.f};

  for (int ks = 0; ks < 8; ++ks) {
    bf16x8 af = *(const bf16x8*)&AO[(size_t)(m0 + lo)*256 + ks*32 + hi*8];
    #pragma unroll
    for (int nt = 0; nt < 4; ++nt) {
      bf16x8 bf = *(const bf16x8*)&Wpt[(size_t)(n0 + nt*16 + lo)*256 + ks*32 + hi*8];
      acc[nt] = __builtin_amdgcn_mfma_f32_16x16x32_bf16(af, bf, acc[nt], 0, 0, 0);
    }
  }

  #pragma unroll
  for (int nt = 0; nt < 4; ++nt) {
    int c = n0 + nt*16 + lo;
    float bpv = bp[c];
    #pragma unroll
    for (int r = 0; r < 4; ++r) {
      size_t o = (size_t)(m0 + hi*4 + r)*HIDD + c;
      out[o] = h[o] + acc[nt][r] + bpv;
    }
  }
}

// ---------------- launch ----------------------------------------------------
extern "C" void kernel_launch(void* const* d_in, const int* in_sizes, int n_in,
                              void* d_out, int out_size, void* d_ws, size_t ws_size,
                              hipStream_t stream)
{
  const float* h     = (const float*)d_in[0];
  const float* coord = (const float*)d_in[1];
  const int*   mask  = (const int*)  d_in[2];
  const float* Wqkv  = (const float*)d_in[3];
  const float* bqkv  = (const float*)d_in[4];
  const float* Wproj = (const float*)d_in[5];
  const float* bproj = (const float*)d_in[6];
  const float* gamma = (const float*)d_in[7];
  const float* beta  = (const float*)d_in[8];
  const float* Wb1   = (const float*)d_in[9];
  const float* bb1   = (const float*)d_in[10];
  const float* Wb2   = (const float*)d_in[11];
  const float* bb2   = (const float*)d_in[12];
  const float* Wb3   = (const float*)d_in[13];
  const float* bb3   = (const float*)d_in[14];
  float* out = (float*)d_out;

  float* ws = (float*)d_ws;
  float*  tmp  = ws;                              // 8*2049 -> pad 16400 floats
  float2* tbl2 = (float2*)(ws + 16400);           // 8*2048 float2
  unsigned short* usbase = (unsigned short*)(ws + 49168);
  unsigned short* wtq  = usbase;                        // 768*256
  unsigned short* wtp  = wtq + 768*256;                 // 256*256
  unsigned short* xln  = wtp + 256*256;                 // 4096*256
  unsigned short* qws  = xln + (size_t)BB*NN*HIDD;
  unsigned short* kws  = qws + (size_t)BB*NHD*NN*DHD;
  unsigned short* vtws = kws + (size_t)BB*NHD*NN*DHD;
  unsigned short* aob  = vtws + (size_t)BB*NHD*NN*DHD;  // 4096*256

  table_kernel<<<dim3(TI2 + 1), dim3(64), 0, stream>>>(Wb1, bb1, Wb2, bb2, Wb3, bb3, tmp);
  tbl_pack_kernel<<<dim3(64), dim3(256), 0, stream>>>(tmp, tbl2);
  wt_kernel<<<dim3(768/16, 16), dim3(256), 0, stream>>>(Wqkv, wtq, 768);
  wt_kernel<<<dim3(256/16, 16), dim3(256), 0, stream>>>(Wproj, wtp, 256);
  ln_kernel<<<dim3(BB*NN/8), dim3(256), 0, stream>>>(h, gamma, beta, xln);
  qkv_mm_kernel<<<dim3(BB*NN/64, 6), dim3(256), 0, stream>>>(xln, wtq, bqkv, qws, kws, vtws);
  attn_kernel<<<dim3(NN/64, BB*NHD), dim3(256), 0, stream>>>(qws, kws, vtws, coord, mask, tbl2, aob);
  proj_mm_kernel<<<dim3(BB*NN/64, 4), dim3(256), 0, stream>>>(aob, wtp, bproj, h, out);
}

// Round 4
// 83.761 us; speedup vs baseline: 2.8419x; 1.0612x over previous
//
#include <hip/hip_runtime.h>
#include <hip/hip_fp16.h>
#include <math.h>

#define BB   4
#define NN   1024
#define HIDD 256
#define NHD  8
#define DHD  32
#define BHD  64
#define TI2  2048          // table intervals over t in [-1,1]
#define LOG2E 1.4426950408889634f

typedef __attribute__((ext_vector_type(8))) short bf16x8;
typedef __attribute__((ext_vector_type(4))) float f32x4;

__device__ __forceinline__ unsigned short f2bf(float x) {
  union { float f; unsigned u; } c; c.f = x;
  unsigned r = c.u + 0x7FFFu + ((c.u >> 16) & 1u);
  return (unsigned short)(r >> 16);
}

// ---------------- Kernel 1a: bias-MLP point values tmp[NH][TI2+1] -----------
__global__ __launch_bounds__(64) void table_kernel(
    const float* __restrict__ Wb1, const float* __restrict__ bb1,
    const float* __restrict__ Wb2, const float* __restrict__ bb2,
    const float* __restrict__ Wb3, const float* __restrict__ bb3,
    float* __restrict__ tmp)
{
  __shared__ float h1[BHD];
  __shared__ float h2[BHD];
  int j  = threadIdx.x;
  int pt = blockIdx.x;                          // 0..TI2
  float t = -1.0f + (float)pt * (2.0f / (float)TI2);
  float z = fmaf(t, Wb1[j], bb1[j]);
  h1[j] = z / (1.0f + __expf(-z));
  __syncthreads();
  float acc = bb2[j];
  #pragma unroll 16
  for (int i = 0; i < BHD; ++i) acc = fmaf(h1[i], Wb2[i*BHD + j], acc);
  h2[j] = acc / (1.0f + __expf(-acc));
  __syncthreads();
  if (j < NHD) {
    float o = bb3[j];
    #pragma unroll 16
    for (int i = 0; i < BHD; ++i) o = fmaf(h2[i], Wb3[i*NHD + j], o);
    tmp[j*(TI2+1) + pt] = o;
  }
}

// ---- Kernel 1b: pack {base, slope} half2, pre-scaled by log2(e) ------------
__global__ __launch_bounds__(256) void tbl_pack_kernel(
    const float* __restrict__ tmp, unsigned* __restrict__ tblh)
{
  int idx  = blockIdx.x * 256 + threadIdx.x;    // 0..8*2048-1
  int head = idx >> 11;
  int i    = idx & 2047;
  float b = tmp[head*(TI2+1) + i] * LOG2E;
  float n = tmp[head*(TI2+1) + i + 1] * LOG2E;
  __half2 hh = __floats2half2_rn(b, n - b);     // x=base, y=slope (log2 units)
  tblh[head*TI2 + i] = *(unsigned*)&hh;
}

// ---------------- Kernel 1c: weight transpose+convert W[k][n] -> Wt[n][k] ---
__global__ __launch_bounds__(256) void wt_kernel(
    const float* __restrict__ W, unsigned short* __restrict__ Wt, int ncols)
{
  __shared__ float t[16][17];
  int sx = threadIdx.x & 15, sy = threadIdx.x >> 4;
  int n0 = blockIdx.x * 16, k0 = blockIdx.y * 16;
  t[sy][sx] = W[(size_t)(k0 + sy) * ncols + n0 + sx];
  __syncthreads();
  Wt[(size_t)(n0 + sy) * 256 + k0 + sx] = f2bf(t[sx][sy]);
}

// ---------------- Kernel 2a: LayerNorm -> xln bf16 [4096][256] --------------
__global__ __launch_bounds__(256) void ln_kernel(
    const float* __restrict__ h, const float* __restrict__ gamma,
    const float* __restrict__ beta, unsigned short* __restrict__ xln)
{
  int tid = threadIdx.x;
  int r = tid >> 5, l32 = tid & 31;
  int g = blockIdx.x * 8 + r;                    // flat row in [0, B*N)
  const float4* hrow = (const float4*)(h + (size_t)g * HIDD);
  float4 xv[2];
  float sum = 0.f, sq = 0.f;
  #pragma unroll
  for (int j = 0; j < 2; ++j) {
    xv[j] = hrow[l32*2 + j];
    sum += xv[j].x + xv[j].y + xv[j].z + xv[j].w;
    sq  += xv[j].x*xv[j].x + xv[j].y*xv[j].y + xv[j].z*xv[j].z + xv[j].w*xv[j].w;
  }
  #pragma unroll
  for (int off = 1; off < 32; off <<= 1) {
    sum += __shfl_xor(sum, off);
    sq  += __shfl_xor(sq,  off);
  }
  float mu  = sum * (1.0f/HIDD);
  float var = sq  * (1.0f/HIDD) - mu*mu;
  float rs  = rsqrtf(var + 1e-5f);
  union { bf16x8 v; unsigned short u[8]; } o;
  #pragma unroll
  for (int j = 0; j < 2; ++j) {
    int k = l32*8 + j*4;
    float4 gv = *(const float4*)&gamma[k];
    float4 bv = *(const float4*)&beta[k];
    o.u[j*4+0] = f2bf(fmaf((xv[j].x - mu)*rs, gv.x, bv.x));
    o.u[j*4+1] = f2bf(fmaf((xv[j].y - mu)*rs, gv.y, bv.y));
    o.u[j*4+2] = f2bf(fmaf((xv[j].z - mu)*rs, gv.z, bv.z));
    o.u[j*4+3] = f2bf(fmaf((xv[j].w - mu)*rs, gv.w, bv.w));
  }
  *(bf16x8*)&xln[(size_t)g*HIDD + l32*8] = o.v;
}

// ---------------- Kernel 2b: MFMA QKV GEMM [4096x256]x[256x768] -------------
__global__ __launch_bounds__(256) void qkv_mm_kernel(
    const unsigned short* __restrict__ X, const unsigned short* __restrict__ Wt,
    const float* __restrict__ bqkv,
    unsigned short* __restrict__ qws, unsigned short* __restrict__ kws,
    unsigned short* __restrict__ vtws)
{
  int tid = threadIdx.x, lane = tid & 63, w = tid >> 6;
  int lo = lane & 15, hi = lane >> 4;
  int m0 = blockIdx.x * 64 + w * 16;             // wave's 16 rows
  int n0 = blockIdx.y * 128;
  f32x4 acc[8];
  #pragma unroll
  for (int nt = 0; nt < 8; ++nt) acc[nt] = (f32x4){0.f,0.f,0.f,0.f};

  for (int ks = 0; ks < 8; ++ks) {
    bf16x8 af = *(const bf16x8*)&X[(size_t)(m0 + lo)*256 + ks*32 + hi*8];
    #pragma unroll
    for (int nt = 0; nt < 8; ++nt) {
      bf16x8 bf = *(const bf16x8*)&Wt[(size_t)(n0 + nt*16 + lo)*256 + ks*32 + hi*8];
      acc[nt] = __builtin_amdgcn_mfma_f32_16x16x32_bf16(af, bf, acc[nt], 0, 0, 0);
    }
  }

  int b = m0 >> 10;
  int nbase = (m0 & 1023) + hi*4;
  #pragma unroll
  for (int nt = 0; nt < 8; ++nt) {
    int c = n0 + nt*16 + lo;
    int cc = c >> 8;                              // uniform per (block, nt)
    int cr = c & 255;
    int head = cr >> 5, d = cr & 31;
    float bq = bqkv[c];
    size_t bh = (size_t)(b*NHD + head);
    #pragma unroll
    for (int r = 0; r < 4; ++r) {
      unsigned short val = f2bf(acc[nt][r] + bq);
      int nl = nbase + r;
      if (cc == 0)      qws[(bh*NN + nl)*DHD + d] = val;
      else if (cc == 1) kws[(bh*NN + nl)*DHD + d] = val;
      else              vtws[(bh*DHD + d)*NN + nl] = val;
    }
  }
}

// ------- Kernel 3: MFMA flash attention, kv-split x2, log2-domain -----------
__global__ __launch_bounds__(256) void attn_kernel(
    const unsigned short* __restrict__ Q, const unsigned short* __restrict__ K,
    const unsigned short* __restrict__ Vt, const float* __restrict__ coord,
    const int* __restrict__ mask, const unsigned* __restrict__ tblh,
    float* __restrict__ pO, float2* __restrict__ pML)
{
  __shared__ unsigned tableL[TI2];                // 8192 B (half2, log2 units)
  __shared__ unsigned short Klds[64][40];
  __shared__ unsigned short Vtlds[32][72];
  __shared__ float2 ckpen[64];
  __shared__ unsigned short Plds[4][16][72];

  int tid = threadIdx.x;
  int lane = tid & 63;
  int w = tid >> 6;
  int bh = blockIdx.y;
  int half = blockIdx.z;
  int b = bh >> 3, head = bh & 7;
  int qbase = blockIdx.x * 64 + w * 16;
  int lo = lane & 15, hi = lane >> 4;

  {
    const uint4* src = (const uint4*)(tblh + head*TI2);
    uint4* dst = (uint4*)tableL;
    for (int i = tid; i < TI2/4; i += 256) dst[i] = src[i];
  }

  bf16x8 qf = *(const bf16x8*)&Q[((size_t)bh*NN + qbase + lo)*DHD + hi*8];
  float4 cq4 = *(const float4*)&coord[b*NN + qbase + hi*4];
  float cq[4] = {cq4.x, cq4.y, cq4.z, cq4.w};

  float mrun[4], lrun[4];
  f32x4 oacc[2];
  #pragma unroll
  for (int r = 0; r < 4; ++r) { mrun[r] = -1e30f; lrun[r] = 0.f; }
  oacc[0] = (f32x4){0.f,0.f,0.f,0.f};
  oacc[1] = (f32x4){0.f,0.f,0.f,0.f};
  const float scale2 = 0.17677669529663689f * LOG2E;  // 1/sqrt(32) * log2(e)

  int kt0 = half * (NN/2);
  for (int kt = kt0; kt < kt0 + NN/2; kt += 64) {
    __syncthreads();                               // prev K/V tile consumed
    {
      int r = tid >> 2, s = tid & 3;
      bf16x8 kv = *(const bf16x8*)&K[((size_t)bh*NN + kt + r)*DHD + s*8];
      *(bf16x8*)&Klds[r][s*8] = kv;
      int r2 = tid >> 3, s2 = tid & 7;
      bf16x8 vv = *(const bf16x8*)&Vt[((size_t)bh*DHD + r2)*NN + kt + s2*8];
      *(bf16x8*)&Vtlds[r2][s2*8] = vv;
      if (tid < 64) {
        float ck = coord[b*NN + kt + tid];
        int mk = mask[b*NN + kt + tid];
        ckpen[tid] = make_float2(ck, mk ? 0.0f : -1e31f);
      }
    }
    __syncthreads();

    f32x4 z = {0.f,0.f,0.f,0.f};
    f32x4 sacc[4];
    #pragma unroll
    for (int nt = 0; nt < 4; ++nt) {
      bf16x8 kf = *(const bf16x8*)&Klds[nt*16 + lo][hi*8];
      sacc[nt] = __builtin_amdgcn_mfma_f32_16x16x32_bf16(qf, kf, z, 0, 0, 0);
    }

    float sv[4][4];
    #pragma unroll
    for (int nt = 0; nt < 4; ++nt) {
      float2 cp = ckpen[nt*16 + lo];
      #pragma unroll
      for (int r = 0; r < 4; ++r) {
        float tt = cp.x - cq[r];
        float u  = fmaf(tt, (float)TI2*0.5f, (float)TI2*0.5f);
        u = fminf(fmaxf(u, 0.0f), (float)TI2 - 0.01f);
        int   i0 = (int)u;
        float fr = u - (float)i0;
        unsigned e = tableL[i0];
        __half2 hh = *(__half2*)&e;
        float bias = fmaf(__high2float(hh), fr, __low2float(hh));
        sv[nt][r] = fmaf(sacc[nt][r], scale2, bias + cp.y);   // log2 units
      }
    }

    #pragma unroll
    for (int r = 0; r < 4; ++r) {
      float pm = fmaxf(fmaxf(sv[0][r], sv[1][r]), fmaxf(sv[2][r], sv[3][r]));
      pm = fmaxf(pm, __shfl_xor(pm, 1));
      pm = fmaxf(pm, __shfl_xor(pm, 2));
      pm = fmaxf(pm, __shfl_xor(pm, 4));
      pm = fmaxf(pm, __shfl_xor(pm, 8));
      float mn = fmaxf(mrun[r], pm);
      float sf = __builtin_amdgcn_exp2f(mrun[r] - mn);
      mrun[r] = mn;
      lrun[r] *= sf;
      oacc[0][r] *= sf;
      oacc[1][r] *= sf;
      float ps = 0.f;
      #pragma unroll
      for (int nt = 0; nt < 4; ++nt) {
        float p = __builtin_amdgcn_exp2f(sv[nt][r] - mn);
        ps += p;
        Plds[w][hi*4 + r][nt*16 + lo] = f2bf(p);
      }
      lrun[r] += ps;
    }
    // no barrier: Plds[w] is wave-private, in-order within the wave

    #pragma unroll
    for (int ks = 0; ks < 2; ++ks) {
      bf16x8 pf = *(const bf16x8*)&Plds[w][lo][ks*32 + hi*8];
      #pragma unroll
      for (int n2 = 0; n2 < 2; ++n2) {
        bf16x8 vf = *(const bf16x8*)&Vtlds[n2*16 + lo][ks*32 + hi*8];
        oacc[n2] = __builtin_amdgcn_mfma_f32_16x16x32_bf16(pf, vf, oacc[n2], 0, 0, 0);
      }
    }
  }

  // epilogue: per-row l reduce; store UNNORMALIZED partial O + (m, l)
  #pragma unroll
  for (int r = 0; r < 4; ++r) {
    float t = lrun[r];
    t += __shfl_xor(t, 1);
    t += __shfl_xor(t, 2);
    t += __shfl_xor(t, 4);
    t += __shfl_xor(t, 8);
    int row = qbase + hi*4 + r;
    size_t base = ((size_t)(half*BB*NHD + bh)*NN + row);
    #pragma unroll
    for (int n2 = 0; n2 < 2; ++n2)
      pO[base*DHD + n2*16 + lo] = oacc[n2][r];
    if (lo == 0) pML[base] = make_float2(mrun[r], t);
  }
}

// ---------------- Kernel 3b: merge the two kv-halves ------------------------
__global__ __launch_bounds__(256) void attn_combine_kernel(
    const float* __restrict__ pO, const float2* __restrict__ pML,
    unsigned short* __restrict__ ao)
{
  int tid = threadIdx.x;
  int rg = blockIdx.x * 8 + (tid >> 5);          // 0..32767 (bh*NN+n)
  int d  = tid & 31;
  int bh = rg >> 10, n = rg & 1023;
  int b = bh >> 3, head = bh & 7;
  float2 ml0 = pML[rg];
  float2 ml1 = pML[(size_t)(BB*NHD)*NN + rg];
  float o0 = pO[(size_t)rg*DHD + d];
  float o1 = pO[((size_t)(BB*NHD)*NN + rg)*DHD + d];
  float mm = fmaxf(ml0.x, ml1.x);
  float e0 = __builtin_amdgcn_exp2f(ml0.x - mm);
  float e1 = __builtin_amdgcn_exp2f(ml1.x - mm);
  float inv = 1.0f / fmaf(ml0.y, e0, ml1.y * e1);
  ao[((size_t)(b*NN + n))*HIDD + head*DHD + d] = f2bf(fmaf(o0, e0, o1*e1) * inv);
}

// ---------------- Kernel 4: MFMA proj GEMM + bias + residual ----------------
__global__ __launch_bounds__(256) void proj_mm_kernel(
    const unsigned short* __restrict__ AO, const unsigned short* __restrict__ Wpt,
    const float* __restrict__ bp, const float* __restrict__ h,
    float* __restrict__ out)
{
  int tid = threadIdx.x, lane = tid & 63, w = tid >> 6;
  int lo = lane & 15, hi = lane >> 4;
  int m0 = blockIdx.x * 64 + w * 16;
  int n0 = blockIdx.y * 64;
  f32x4 acc[4];
  #pragma unroll
  for (int nt = 0; nt < 4; ++nt) acc[nt] = (f32x4){0.f,0.f,0.f,0.f};

  for (int ks = 0; ks < 8; ++ks) {
    bf16x8 af = *(const bf16x8*)&AO[(size_t)(m0 + lo)*256 + ks*32 + hi*8];
    #pragma unroll
    for (int nt = 0; nt < 4; ++nt) {
      bf16x8 bf = *(const bf16x8*)&Wpt[(size_t)(n0 + nt*16 + lo)*256 + ks*32 + hi*8];
      acc[nt] = __builtin_amdgcn_mfma_f32_16x16x32_bf16(af, bf, acc[nt], 0, 0, 0);
    }
  }

  #pragma unroll
  for (int nt = 0; nt < 4; ++nt) {
    int c = n0 + nt*16 + lo;
    float bpv = bp[c];
    #pragma unroll
    for (int r = 0; r < 4; ++r) {
      size_t o = (size_t)(m0 + hi*4 + r)*HIDD + c;
      out[o] = h[o] + acc[nt][r] + bpv;
    }
  }
}

// ---------------- launch ----------------------------------------------------
extern "C" void kernel_launch(void* const* d_in, const int* in_sizes, int n_in,
                              void* d_out, int out_size, void* d_ws, size_t ws_size,
                              hipStream_t stream)
{
  const float* h     = (const float*)d_in[0];
  const float* coord = (const float*)d_in[1];
  const int*   mask  = (const int*)  d_in[2];
  const float* Wqkv  = (const float*)d_in[3];
  const float* bqkv  = (const float*)d_in[4];
  const float* Wproj = (const float*)d_in[5];
  const float* bproj = (const float*)d_in[6];
  const float* gamma = (const float*)d_in[7];
  const float* beta  = (const float*)d_in[8];
  const float* Wb1   = (const float*)d_in[9];
  const float* bb1   = (const float*)d_in[10];
  const float* Wb2   = (const float*)d_in[11];
  const float* bb2   = (const float*)d_in[12];
  const float* Wb3   = (const float*)d_in[13];
  const float* bb3   = (const float*)d_in[14];
  float* out = (float*)d_out;

  float* ws = (float*)d_ws;
  float*    tmp  = ws;                            // 16400 floats
  unsigned* tblh = (unsigned*)(ws + 16400);       // 8*2048 uints
  unsigned short* usbase = (unsigned short*)(ws + 16400 + 16384);
  unsigned short* wtq  = usbase;                        // 768*256
  unsigned short* wtp  = wtq + 768*256;                 // 256*256
  unsigned short* xln  = wtp + 256*256;                 // 4096*256
  unsigned short* qws  = xln + (size_t)BB*NN*HIDD;
  unsigned short* kws  = qws + (size_t)BB*NHD*NN*DHD;
  unsigned short* vtws = kws + (size_t)BB*NHD*NN*DHD;
  unsigned short* aob  = vtws + (size_t)BB*NHD*NN*DHD;  // 4096*256
  float*  pO  = (float*)(aob + (size_t)BB*NN*HIDD);     // 2*32*1024*32 floats
  float2* pML = (float2*)(pO + (size_t)2*BB*NHD*NN*DHD);// 2*32*1024 float2

  table_kernel<<<dim3(TI2 + 1), dim3(64), 0, stream>>>(Wb1, bb1, Wb2, bb2, Wb3, bb3, tmp);
  tbl_pack_kernel<<<dim3(64), dim3(256), 0, stream>>>(tmp, tblh);
  wt_kernel<<<dim3(768/16, 16), dim3(256), 0, stream>>>(Wqkv, wtq, 768);
  wt_kernel<<<dim3(256/16, 16), dim3(256), 0, stream>>>(Wproj, wtp, 256);
  ln_kernel<<<dim3(BB*NN/8), dim3(256), 0, stream>>>(h, gamma, beta, xln);
  qkv_mm_kernel<<<dim3(BB*NN/64, 6), dim3(256), 0, stream>>>(xln, wtq, bqkv, qws, kws, vtws);
  attn_kernel<<<dim3(NN/64, BB*NHD, 2), dim3(256), 0, stream>>>(qws, kws, vtws, coord, mask, tblh, pO, pML);
  attn_combine_kernel<<<dim3(BB*NHD*NN/8), dim3(256), 0, stream>>>(pO, pML, aob);
  proj_mm_kernel<<<dim3(BB*NN/64, 4), dim3(256), 0, stream>>>(aob, wtp, bproj, h, out);
}

// Round 5
// 83.342 us; speedup vs baseline: 2.8562x; 1.0050x over previous
//
#include <hip/hip_runtime.h>
#include <hip/hip_fp16.h>
#include <math.h>

#define BB   4
#define NN   1024
#define HIDD 256
#define NHD  8
#define DHD  32
#define BHD  64
#define TI2  2048          // table intervals over t in [-1,1]
#define LOG2E 1.4426950408889634f

typedef __attribute__((ext_vector_type(8))) short bf16x8;
typedef __attribute__((ext_vector_type(4))) float f32x4;
typedef __attribute__((ext_vector_type(4))) unsigned short u16x4;

__device__ __forceinline__ unsigned short f2bf(float x) {
  union { float f; unsigned u; } c; c.f = x;
  unsigned r = c.u + 0x7FFFu + ((c.u >> 16) & 1u);
  return (unsigned short)(r >> 16);
}
__device__ __forceinline__ float bf2f(unsigned short b) {
  union { unsigned u; float f; } c; c.u = ((unsigned)b) << 16;
  return c.f;
}

// ---- Kernel 1: prep = bias-table {base,slope} + both weight transposes -----
// blocks 0..511    : table, 4 pts each (evaluate f at pt and pt+1)
// blocks 512..1279 : Wqkv [256][768] -> wtq bf16 [768][256]
// blocks 1280..1535: Wproj [256][256] -> wtp bf16 [256][256]
__global__ __launch_bounds__(256) void prep_kernel(
    const float* __restrict__ Wb1, const float* __restrict__ bb1,
    const float* __restrict__ Wb2, const float* __restrict__ bb2,
    const float* __restrict__ Wb3, const float* __restrict__ bb3,
    const float* __restrict__ Wqkv, const float* __restrict__ Wproj,
    unsigned* __restrict__ tblh, unsigned short* __restrict__ wtq,
    unsigned short* __restrict__ wtp)
{
  __shared__ float h1a[4][64], h1b[4][64], h2a[4][64], h2b[4][64];
  __shared__ float t[16][17];
  int bid = blockIdx.x, tid = threadIdx.x;
  if (bid < 512) {
    int g = tid >> 6, j = tid & 63;
    int pt = bid * 4 + g;
    float t0 = -1.0f + (float)pt     * (2.0f / (float)TI2);
    float t1 = -1.0f + (float)(pt+1) * (2.0f / (float)TI2);
    float w1 = Wb1[j], c1 = bb1[j];
    float z0 = fmaf(t0, w1, c1), z1 = fmaf(t1, w1, c1);
    h1a[g][j] = z0 / (1.0f + __expf(-z0));
    h1b[g][j] = z1 / (1.0f + __expf(-z1));
    __syncthreads();
    float a0 = bb2[j], a1 = a0;
    #pragma unroll 16
    for (int i = 0; i < BHD; ++i) {
      float wv = Wb2[i*BHD + j];
      a0 = fmaf(h1a[g][i], wv, a0);
      a1 = fmaf(h1b[g][i], wv, a1);
    }
    h2a[g][j] = a0 / (1.0f + __expf(-a0));
    h2b[g][j] = a1 / (1.0f + __expf(-a1));
    __syncthreads();
    if (j < NHD) {
      float o0 = bb3[j], o1 = o0;
      #pragma unroll 16
      for (int i = 0; i < BHD; ++i) {
        float wv = Wb3[i*NHD + j];
        o0 = fmaf(h2a[g][i], wv, o0);
        o1 = fmaf(h2b[g][i], wv, o1);
      }
      o0 *= LOG2E; o1 *= LOG2E;
      __half2 hh = __floats2half2_rn(o0, o1 - o0);   // {base, slope}, log2 units
      tblh[j*TI2 + pt] = *(unsigned*)&hh;
    }
  } else {
    const float* W; unsigned short* Wt; int n0, k0, ncols;
    if (bid < 1280) {
      int rb = bid - 512;                 // 768 blocks: 48 x 16
      n0 = (rb % 48) * 16; k0 = (rb / 48) * 16; ncols = 768;
      W = Wqkv; Wt = wtq;
    } else {
      int rc = bid - 1280;                // 256 blocks: 16 x 16
      n0 = (rc & 15) * 16; k0 = (rc >> 4) * 16; ncols = 256;
      W = Wproj; Wt = wtp;
    }
    int sx = tid & 15, sy = tid >> 4;
    t[sy][sx] = W[(size_t)(k0 + sy) * ncols + n0 + sx];
    __syncthreads();
    Wt[(size_t)(n0 + sy) * 256 + k0 + sx] = f2bf(t[sx][sy]);
  }
}

// ---- Kernel 2: fused LayerNorm + MFMA QKV GEMM [4096x256]x[256x768] --------
__global__ __launch_bounds__(256) void ln_qkv_mm_kernel(
    const float* __restrict__ h, const float* __restrict__ gamma,
    const float* __restrict__ beta, const unsigned short* __restrict__ Wt,
    const float* __restrict__ bqkv,
    unsigned short* __restrict__ qws, unsigned short* __restrict__ kws,
    unsigned short* __restrict__ vtws)
{
  __shared__ unsigned short xs[64][260];    // pad 4: row stride 130 dw = 2 mod 32
  int tid = threadIdx.x;
  int m0 = blockIdx.x * 64, n0 = blockIdx.y * 128;

  // --- LN of rows m0..m0+63 into xs (4 threads/row, 64 cols each) ---
  {
    int r = tid >> 2, q = tid & 3;
    const float* hrow = h + (size_t)(m0 + r)*HIDD + q*64;
    float4 xv[16];
    float sum = 0.f, sq = 0.f;
    #pragma unroll
    for (int j = 0; j < 16; ++j) {
      xv[j] = *(const float4*)&hrow[j*4];
      sum += xv[j].x + xv[j].y + xv[j].z + xv[j].w;
      sq  += xv[j].x*xv[j].x + xv[j].y*xv[j].y + xv[j].z*xv[j].z + xv[j].w*xv[j].w;
    }
    sum += __shfl_xor(sum, 1); sq += __shfl_xor(sq, 1);
    sum += __shfl_xor(sum, 2); sq += __shfl_xor(sq, 2);
    float mu  = sum * (1.0f/HIDD);
    float var = sq  * (1.0f/HIDD) - mu*mu;
    float rs  = rsqrtf(var + 1e-5f);
    #pragma unroll
    for (int j2 = 0; j2 < 8; ++j2) {
      union { bf16x8 v; unsigned short u[8]; } o;
      #pragma unroll
      for (int e = 0; e < 2; ++e) {
        float4 x4 = xv[j2*2 + e];
        int col = q*64 + j2*8 + e*4;
        float4 gv = *(const float4*)&gamma[col];
        float4 bv = *(const float4*)&beta[col];
        o.u[e*4+0] = f2bf(fmaf((x4.x - mu)*rs, gv.x, bv.x));
        o.u[e*4+1] = f2bf(fmaf((x4.y - mu)*rs, gv.y, bv.y));
        o.u[e*4+2] = f2bf(fmaf((x4.z - mu)*rs, gv.z, bv.z));
        o.u[e*4+3] = f2bf(fmaf((x4.w - mu)*rs, gv.w, bv.w));
      }
      *(bf16x8*)&xs[r][q*64 + j2*8] = o.v;
    }
  }
  __syncthreads();

  // --- GEMM: wave w -> rows m0+w*16..+15, cols n0..n0+127 ---
  int lane = tid & 63, w = tid >> 6;
  int lo = lane & 15, hi = lane >> 4;
  int m0w = m0 + w*16;
  f32x4 acc[8];
  #pragma unroll
  for (int nt = 0; nt < 8; ++nt) acc[nt] = (f32x4){0.f,0.f,0.f,0.f};

  #pragma unroll
  for (int ks = 0; ks < 8; ++ks) {
    bf16x8 af = *(const bf16x8*)&xs[w*16 + lo][ks*32 + hi*8];
    #pragma unroll
    for (int nt = 0; nt < 8; ++nt) {
      bf16x8 bf = *(const bf16x8*)&Wt[(size_t)(n0 + nt*16 + lo)*256 + ks*32 + hi*8];
      acc[nt] = __builtin_amdgcn_mfma_f32_16x16x32_bf16(af, bf, acc[nt], 0, 0, 0);
    }
  }

  int b = m0w >> 10;
  int nbase = (m0w & 1023) + hi*4;
  #pragma unroll
  for (int nt = 0; nt < 8; ++nt) {
    int c = n0 + nt*16 + lo;
    int cc = c >> 8;                              // uniform per (block, nt)
    int cr = c & 255;
    int head = cr >> 5, d = cr & 31;
    float bq = bqkv[c];
    size_t bh = (size_t)(b*NHD + head);
    #pragma unroll
    for (int r = 0; r < 4; ++r) {
      unsigned short val = f2bf(acc[nt][r] + bq);
      int nl = nbase + r;
      if (cc == 0)      qws[(bh*NN + nl)*DHD + d] = val;
      else if (cc == 1) kws[(bh*NN + nl)*DHD + d] = val;
      else              vtws[(bh*DHD + d)*NN + nl] = val;
    }
  }
}

// ------- Kernel 3: MFMA flash attention, kv-split x2, log2-domain -----------
__global__ __launch_bounds__(256) void attn_kernel(
    const unsigned short* __restrict__ Q, const unsigned short* __restrict__ K,
    const unsigned short* __restrict__ Vt, const float* __restrict__ coord,
    const int* __restrict__ mask, const unsigned* __restrict__ tblh,
    unsigned short* __restrict__ pO, float2* __restrict__ pML)
{
  __shared__ unsigned tableL[TI2];                // 8192 B (half2, log2 units)
  __shared__ unsigned short Klds[64][40];
  __shared__ unsigned short Vtlds[32][72];
  __shared__ float2 ckpen[64];
  __shared__ unsigned short Plds[4][16][72];

  int tid = threadIdx.x;
  int lane = tid & 63;
  int w = tid >> 6;
  int bh = blockIdx.y;
  int half = blockIdx.z;
  int b = bh >> 3, head = bh & 7;
  int qbase = blockIdx.x * 64 + w * 16;
  int lo = lane & 15, hi = lane >> 4;

  {
    const uint4* src = (const uint4*)(tblh + head*TI2);
    uint4* dst = (uint4*)tableL;
    for (int i = tid; i < TI2/4; i += 256) dst[i] = src[i];
  }

  bf16x8 qf = *(const bf16x8*)&Q[((size_t)bh*NN + qbase + lo)*DHD + hi*8];
  float4 cq4 = *(const float4*)&coord[b*NN + qbase + hi*4];
  float cq[4] = {cq4.x, cq4.y, cq4.z, cq4.w};

  float mrun[4], lrun[4];
  f32x4 oacc[2];
  #pragma unroll
  for (int r = 0; r < 4; ++r) { mrun[r] = -1e30f; lrun[r] = 0.f; }
  oacc[0] = (f32x4){0.f,0.f,0.f,0.f};
  oacc[1] = (f32x4){0.f,0.f,0.f,0.f};
  const float scale2 = 0.17677669529663689f * LOG2E;  // 1/sqrt(32) * log2(e)

  int kt0 = half * (NN/2);
  for (int kt = kt0; kt < kt0 + NN/2; kt += 64) {
    __syncthreads();                               // prev K/V tile consumed
    {
      int r = tid >> 2, s = tid & 3;
      bf16x8 kv = *(const bf16x8*)&K[((size_t)bh*NN + kt + r)*DHD + s*8];
      *(bf16x8*)&Klds[r][s*8] = kv;
      int r2 = tid >> 3, s2 = tid & 7;
      bf16x8 vv = *(const bf16x8*)&Vt[((size_t)bh*DHD + r2)*NN + kt + s2*8];
      *(bf16x8*)&Vtlds[r2][s2*8] = vv;
      if (tid < 64) {
        float ck = coord[b*NN + kt + tid];
        int mk = mask[b*NN + kt + tid];
        ckpen[tid] = make_float2(ck, mk ? 0.0f : -1e31f);
      }
    }
    __syncthreads();

    f32x4 z = {0.f,0.f,0.f,0.f};
    f32x4 sacc[4];
    #pragma unroll
    for (int nt = 0; nt < 4; ++nt) {
      bf16x8 kf = *(const bf16x8*)&Klds[nt*16 + lo][hi*8];
      sacc[nt] = __builtin_amdgcn_mfma_f32_16x16x32_bf16(qf, kf, z, 0, 0, 0);
    }

    float sv[4][4];
    #pragma unroll
    for (int nt = 0; nt < 4; ++nt) {
      float2 cp = ckpen[nt*16 + lo];
      #pragma unroll
      for (int r = 0; r < 4; ++r) {
        float tt = cp.x - cq[r];
        float u  = fmaf(tt, (float)TI2*0.5f, (float)TI2*0.5f);
        u = fminf(fmaxf(u, 0.0f), (float)TI2 - 0.01f);
        int   i0 = (int)u;
        float fr = u - (float)i0;
        unsigned e = tableL[i0];
        __half2 hh = *(__half2*)&e;
        float bias = fmaf(__high2float(hh), fr, __low2float(hh));
        sv[nt][r] = fmaf(sacc[nt][r], scale2, bias + cp.y);   // log2 units
      }
    }

    #pragma unroll
    for (int r = 0; r < 4; ++r) {
      float pm = fmaxf(fmaxf(sv[0][r], sv[1][r]), fmaxf(sv[2][r], sv[3][r]));
      pm = fmaxf(pm, __shfl_xor(pm, 1));
      pm = fmaxf(pm, __shfl_xor(pm, 2));
      pm = fmaxf(pm, __shfl_xor(pm, 4));
      pm = fmaxf(pm, __shfl_xor(pm, 8));
      float mn = fmaxf(mrun[r], pm);
      float sf = __builtin_amdgcn_exp2f(mrun[r] - mn);
      mrun[r] = mn;
      lrun[r] *= sf;
      oacc[0][r] *= sf;
      oacc[1][r] *= sf;
      float ps = 0.f;
      #pragma unroll
      for (int nt = 0; nt < 4; ++nt) {
        float p = __builtin_amdgcn_exp2f(sv[nt][r] - mn);
        ps += p;
        Plds[w][hi*4 + r][nt*16 + lo] = f2bf(p);
      }
      lrun[r] += ps;
    }
    // no barrier: Plds[w] is wave-private, in-order within the wave

    #pragma unroll
    for (int ks = 0; ks < 2; ++ks) {
      bf16x8 pf = *(const bf16x8*)&Plds[w][lo][ks*32 + hi*8];
      #pragma unroll
      for (int n2 = 0; n2 < 2; ++n2) {
        bf16x8 vf = *(const bf16x8*)&Vtlds[n2*16 + lo][ks*32 + hi*8];
        oacc[n2] = __builtin_amdgcn_mfma_f32_16x16x32_bf16(pf, vf, oacc[n2], 0, 0, 0);
      }
    }
  }

  // epilogue: per-row l reduce; store UNNORMALIZED bf16 partial O + (m, l)
  #pragma unroll
  for (int r = 0; r < 4; ++r) {
    float t = lrun[r];
    t += __shfl_xor(t, 1);
    t += __shfl_xor(t, 2);
    t += __shfl_xor(t, 4);
    t += __shfl_xor(t, 8);
    int row = qbase + hi*4 + r;
    size_t base = ((size_t)(half*BB*NHD + bh)*NN + row);
    #pragma unroll
    for (int n2 = 0; n2 < 2; ++n2)
      pO[base*DHD + n2*16 + lo] = f2bf(oacc[n2][r]);
    if (lo == 0) pML[base] = make_float2(mrun[r], t);
  }
}

// ---------------- Kernel 3b: merge the two kv-halves ------------------------
__global__ __launch_bounds__(256) void attn_combine_kernel(
    const unsigned short* __restrict__ pO, const float2* __restrict__ pML,
    unsigned short* __restrict__ ao)
{
  int tid = threadIdx.x;
  int rg = blockIdx.x * 32 + (tid >> 3);         // 0..32767 (bh*NN+n)
  int d4 = (tid & 7) * 4;
  int bh = rg >> 10, n = rg & 1023;
  int b = bh >> 3, head = bh & 7;
  float2 ml0 = pML[rg];
  float2 ml1 = pML[(size_t)(BB*NHD)*NN + rg];
  u16x4 o0 = *(const u16x4*)&pO[(size_t)rg*DHD + d4];
  u16x4 o1 = *(const u16x4*)&pO[((size_t)(BB*NHD)*NN + rg)*DHD + d4];
  float mm = fmaxf(ml0.x, ml1.x);
  float e0 = __builtin_amdgcn_exp2f(ml0.x - mm);
  float e1 = __builtin_amdgcn_exp2f(ml1.x - mm);
  float inv = 1.0f / fmaf(ml0.y, e0, ml1.y * e1);
  u16x4 r;
  #pragma unroll
  for (int i = 0; i < 4; ++i)
    r[i] = f2bf(fmaf(bf2f(o0[i]), e0, bf2f(o1[i]) * e1) * inv);
  *(u16x4*)&ao[((size_t)(b*NN + n))*HIDD + head*DHD + d4] = r;
}

// ---------------- Kernel 4: MFMA proj GEMM + bias + residual ----------------
__global__ __launch_bounds__(256) void proj_mm_kernel(
    const unsigned short* __restrict__ AO, const unsigned short* __restrict__ Wpt,
    const float* __restrict__ bp, const float* __restrict__ h,
    float* __restrict__ out)
{
  int tid = threadIdx.x, lane = tid & 63, w = tid >> 6;
  int lo = lane & 15, hi = lane >> 4;
  int m0 = blockIdx.x * 64 + w * 16;
  int n0 = blockIdx.y * 64;
  f32x4 acc[4];
  #pragma unroll
  for (int nt = 0; nt < 4; ++nt) acc[nt] = (f32x4){0.f,0.f,0.f,0.f};

  #pragma unroll
  for (int ks = 0; ks < 8; ++ks) {
    bf16x8 af = *(const bf16x8*)&AO[(size_t)(m0 + lo)*256 + ks*32 + hi*8];
    #pragma unroll
    for (int nt = 0; nt < 4; ++nt) {
      bf16x8 bf = *(const bf16x8*)&Wpt[(size_t)(n0 + nt*16 + lo)*256 + ks*32 + hi*8];
      acc[nt] = __builtin_amdgcn_mfma_f32_16x16x32_bf16(af, bf, acc[nt], 0, 0, 0);
    }
  }

  #pragma unroll
  for (int nt = 0; nt < 4; ++nt) {
    int c = n0 + nt*16 + lo;
    float bpv = bp[c];
    #pragma unroll
    for (int r = 0; r < 4; ++r) {
      size_t o = (size_t)(m0 + hi*4 + r)*HIDD + c;
      out[o] = h[o] + acc[nt][r] + bpv;
    }
  }
}

// ---------------- launch ----------------------------------------------------
extern "C" void kernel_launch(void* const* d_in, const int* in_sizes, int n_in,
                              void* d_out, int out_size, void* d_ws, size_t ws_size,
                              hipStream_t stream)
{
  const float* h     = (const float*)d_in[0];
  const float* coord = (const float*)d_in[1];
  const int*   mask  = (const int*)  d_in[2];
  const float* Wqkv  = (const float*)d_in[3];
  const float* bqkv  = (const float*)d_in[4];
  const float* Wproj = (const float*)d_in[5];
  const float* bproj = (const float*)d_in[6];
  const float* gamma = (const float*)d_in[7];
  const float* beta  = (const float*)d_in[8];
  const float* Wb1   = (const float*)d_in[9];
  const float* bb1   = (const float*)d_in[10];
  const float* Wb2   = (const float*)d_in[11];
  const float* bb2   = (const float*)d_in[12];
  const float* Wb3   = (const float*)d_in[13];
  const float* bb3   = (const float*)d_in[14];
  float* out = (float*)d_out;

  unsigned* tblh = (unsigned*)d_ws;                     // 8*2048 u32 = 64 KB
  float2*   pML  = (float2*)(tblh + NHD*TI2);           // 2*32*1024 f2 = 512 KB
  unsigned short* wtq  = (unsigned short*)(pML + (size_t)2*BB*NHD*NN);
  unsigned short* wtp  = wtq + 768*256;
  unsigned short* qws  = wtp + 256*256;
  unsigned short* kws  = qws + (size_t)BB*NHD*NN*DHD;   // 1 Mi elems each
  unsigned short* vtws = kws + (size_t)BB*NHD*NN*DHD;
  unsigned short* aob  = vtws + (size_t)BB*NHD*NN*DHD;
  unsigned short* pO   = aob + (size_t)BB*NN*HIDD;      // 2 Mi elems (bf16)

  prep_kernel<<<dim3(1536), dim3(256), 0, stream>>>(
      Wb1, bb1, Wb2, bb2, Wb3, bb3, Wqkv, Wproj, tblh, wtq, wtp);
  ln_qkv_mm_kernel<<<dim3(BB*NN/64, 6), dim3(256), 0, stream>>>(
      h, gamma, beta, wtq, bqkv, qws, kws, vtws);
  attn_kernel<<<dim3(NN/64, BB*NHD, 2), dim3(256), 0, stream>>>(
      qws, kws, vtws, coord, mask, tblh, pO, pML);
  attn_combine_kernel<<<dim3(BB*NHD*NN/32), dim3(256), 0, stream>>>(pO, pML, aob);
  proj_mm_kernel<<<dim3(BB*NN/64, 4), dim3(256), 0, stream>>>(aob, wtp, bproj, h, out);
}

// Round 7
// 77.082 us; speedup vs baseline: 3.0882x; 1.0812x over previous
//
#include <hip/hip_runtime.h>
#include <hip/hip_fp16.h>
#include <math.h>

#define BB   4
#define NN   1024
#define HIDD 256
#define NHD  8
#define DHD  32
#define BHD  64
#define TI2  2048          // table intervals over t in [-1,1]
#define LOG2E 1.4426950408889634f

typedef __attribute__((ext_vector_type(8))) short bf16x8;
typedef __attribute__((ext_vector_type(4))) short bf16x4;
typedef __attribute__((ext_vector_type(4))) float f32x4;

__device__ __forceinline__ unsigned short f2bf(float x) {
  union { float f; unsigned u; } c; c.f = x;
  unsigned r = c.u + 0x7FFFu + ((c.u >> 16) & 1u);
  return (unsigned short)(r >> 16);
}
__device__ __forceinline__ float bf2f(unsigned short b) {
  union { unsigned u; float f; } c; c.u = ((unsigned)b) << 16;
  return c.f;
}

// PV micro-op: oacc += V^T-frag (A) . P^T-frag (B), 16x16x16 bf16.
// Intrinsic preferred (compiler handles MFMA<->VALU hazards). Fallback asm
// pads with s_nop per CDNA hazard rules (VALU-write->MFMA-read: 2;
// MFMA-write->VALU-read: ~8).
__device__ __forceinline__ void pv_mfma(f32x4& acc, bf16x4 a, bf16x4 b) {
#if __has_builtin(__builtin_amdgcn_mfma_f32_16x16x16bf16_1k)
  acc = __builtin_amdgcn_mfma_f32_16x16x16bf16_1k(a, b, acc, 0, 0, 0);
#else
  asm volatile("s_nop 1\n\t"
               "v_mfma_f32_16x16x16_bf16 %0, %1, %2, %0\n\t"
               "s_nop 7\n\t"
               "s_nop 3"
               : "+v"(acc) : "v"(a), "v"(b));
#endif
}

// ---- Kernel 1: prep = bias-table {base,slope} + both weight transposes -----
__global__ __launch_bounds__(256) void prep_kernel(
    const float* __restrict__ Wb1, const float* __restrict__ bb1,
    const float* __restrict__ Wb2, const float* __restrict__ bb2,
    const float* __restrict__ Wb3, const float* __restrict__ bb3,
    const float* __restrict__ Wqkv, const float* __restrict__ Wproj,
    unsigned* __restrict__ tblh, unsigned short* __restrict__ wtq,
    unsigned short* __restrict__ wtp)
{
  __shared__ float h1a[4][64], h1b[4][64], h2a[4][64], h2b[4][64];
  __shared__ float t[16][17];
  int bid = blockIdx.x, tid = threadIdx.x;
  if (bid < 512) {
    int g = tid >> 6, j = tid & 63;
    int pt = bid * 4 + g;
    float t0 = -1.0f + (float)pt     * (2.0f / (float)TI2);
    float t1 = -1.0f + (float)(pt+1) * (2.0f / (float)TI2);
    float w1 = Wb1[j], c1 = bb1[j];
    float z0 = fmaf(t0, w1, c1), z1 = fmaf(t1, w1, c1);
    h1a[g][j] = z0 / (1.0f + __expf(-z0));
    h1b[g][j] = z1 / (1.0f + __expf(-z1));
    __syncthreads();
    float a0 = bb2[j], a1 = a0;
    #pragma unroll 16
    for (int i = 0; i < BHD; ++i) {
      float wv = Wb2[i*BHD + j];
      a0 = fmaf(h1a[g][i], wv, a0);
      a1 = fmaf(h1b[g][i], wv, a1);
    }
    h2a[g][j] = a0 / (1.0f + __expf(-a0));
    h2b[g][j] = a1 / (1.0f + __expf(-a1));
    __syncthreads();
    if (j < NHD) {
      float o0 = bb3[j], o1 = o0;
      #pragma unroll 16
      for (int i = 0; i < BHD; ++i) {
        float wv = Wb3[i*NHD + j];
        o0 = fmaf(h2a[g][i], wv, o0);
        o1 = fmaf(h2b[g][i], wv, o1);
      }
      o0 *= LOG2E; o1 *= LOG2E;
      __half2 hh = __floats2half2_rn(o0, o1 - o0);   // {base, slope}, log2 units
      tblh[j*TI2 + pt] = *(unsigned*)&hh;
    }
  } else {
    const float* W; unsigned short* Wt; int n0, k0, ncols;
    if (bid < 1280) {
      int rb = bid - 512;                 // 768 blocks: 48 x 16
      n0 = (rb % 48) * 16; k0 = (rb / 48) * 16; ncols = 768;
      W = Wqkv; Wt = wtq;
    } else {
      int rc = bid - 1280;                // 256 blocks: 16 x 16
      n0 = (rc & 15) * 16; k0 = (rc >> 4) * 16; ncols = 256;
      W = Wproj; Wt = wtp;
    }
    int sx = tid & 15, sy = tid >> 4;
    t[sy][sx] = W[(size_t)(k0 + sy) * ncols + n0 + sx];
    __syncthreads();
    Wt[(size_t)(n0 + sy) * 256 + k0 + sx] = f2bf(t[sx][sy]);
  }
}

// ---- Kernel 2: fused LayerNorm + MFMA QKV GEMM [4096x256]x[256x768] --------
__global__ __launch_bounds__(256) void ln_qkv_mm_kernel(
    const float* __restrict__ h, const float* __restrict__ gamma,
    const float* __restrict__ beta, const unsigned short* __restrict__ Wt,
    const float* __restrict__ bqkv,
    unsigned short* __restrict__ qws, unsigned short* __restrict__ kws,
    unsigned short* __restrict__ vtws)
{
  __shared__ unsigned short xs[64][260];    // pad 4: row stride 130 dw = 2 mod 32
  int tid = threadIdx.x;
  int m0 = blockIdx.x * 64, n0 = blockIdx.y * 128;

  // --- LN of rows m0..m0+63 into xs (4 threads/row, 64 cols each) ---
  {
    int r = tid >> 2, q = tid & 3;
    const float* hrow = h + (size_t)(m0 + r)*HIDD + q*64;
    float4 xv[16];
    float sum = 0.f, sq = 0.f;
    #pragma unroll
    for (int j = 0; j < 16; ++j) {
      xv[j] = *(const float4*)&hrow[j*4];
      sum += xv[j].x + xv[j].y + xv[j].z + xv[j].w;
      sq  += xv[j].x*xv[j].x + xv[j].y*xv[j].y + xv[j].z*xv[j].z + xv[j].w*xv[j].w;
    }
    sum += __shfl_xor(sum, 1); sq += __shfl_xor(sq, 1);
    sum += __shfl_xor(sum, 2); sq += __shfl_xor(sq, 2);
    float mu  = sum * (1.0f/HIDD);
    float var = sq  * (1.0f/HIDD) - mu*mu;
    float rs  = rsqrtf(var + 1e-5f);
    #pragma unroll
    for (int j2 = 0; j2 < 8; ++j2) {
      union { bf16x8 v; unsigned short u[8]; } o;
      #pragma unroll
      for (int e = 0; e < 2; ++e) {
        float4 x4 = xv[j2*2 + e];
        int col = q*64 + j2*8 + e*4;
        float4 gv = *(const float4*)&gamma[col];
        float4 bv = *(const float4*)&beta[col];
        o.u[e*4+0] = f2bf(fmaf((x4.x - mu)*rs, gv.x, bv.x));
        o.u[e*4+1] = f2bf(fmaf((x4.y - mu)*rs, gv.y, bv.y));
        o.u[e*4+2] = f2bf(fmaf((x4.z - mu)*rs, gv.z, bv.z));
        o.u[e*4+3] = f2bf(fmaf((x4.w - mu)*rs, gv.w, bv.w));
      }
      *(bf16x8*)&xs[r][q*64 + j2*8] = o.v;
    }
  }
  __syncthreads();

  // --- GEMM: wave w -> rows m0+w*16..+15, cols n0..n0+127 ---
  int lane = tid & 63, w = tid >> 6;
  int lo = lane & 15, hi = lane >> 4;
  int m0w = m0 + w*16;
  f32x4 acc[8];
  #pragma unroll
  for (int nt = 0; nt < 8; ++nt) acc[nt] = (f32x4){0.f,0.f,0.f,0.f};

  #pragma unroll
  for (int ks = 0; ks < 8; ++ks) {
    bf16x8 af = *(const bf16x8*)&xs[w*16 + lo][ks*32 + hi*8];
    #pragma unroll
    for (int nt = 0; nt < 8; ++nt) {
      bf16x8 bf = *(const bf16x8*)&Wt[(size_t)(n0 + nt*16 + lo)*256 + ks*32 + hi*8];
      acc[nt] = __builtin_amdgcn_mfma_f32_16x16x32_bf16(af, bf, acc[nt], 0, 0, 0);
    }
  }

  int b = m0w >> 10;
  int nbase = (m0w & 1023) + hi*4;
  #pragma unroll
  for (int nt = 0; nt < 8; ++nt) {
    int c = n0 + nt*16 + lo;
    int cc = c >> 8;                              // uniform per (block, nt)
    int cr = c & 255;
    int head = cr >> 5, d = cr & 31;
    float bq = bqkv[c];
    size_t bh = (size_t)(b*NHD + head);
    #pragma unroll
    for (int r = 0; r < 4; ++r) {
      unsigned short val = f2bf(acc[nt][r] + bq);
      int nl = nbase + r;
      if (cc == 0)      qws[(bh*NN + nl)*DHD + d] = val;
      else if (cc == 1) kws[(bh*NN + nl)*DHD + d] = val;
      else              vtws[(bh*DHD + d)*NN + nl] = val;
    }
  }
}

// ------- Kernel 3: swapped-operand MFMA flash attention ---------------------
// S^T = mfma(K,Q): lane owns q=lane&15, k=hi*4+r (+16nt). Softmax row is
// lane-local (15 fmax + 2 shfl). P stays in registers: S^T D-layout == B-frag
// layout of mfma_f32_16x16x16_bf16 => O^T = V^T . P^T with no cross-lane.
__global__ __launch_bounds__(256, 4) void attn_kernel(
    const unsigned short* __restrict__ Q, const unsigned short* __restrict__ K,
    const unsigned short* __restrict__ Vt, const float* __restrict__ coord,
    const int* __restrict__ mask, const unsigned* __restrict__ tblh,
    unsigned short* __restrict__ pO, float2* __restrict__ pML)
{
  __shared__ unsigned tableL[TI2];                 // 8 KB (half2, log2 units)
  __shared__ unsigned short Klds[2][64][40];       // 10 KB (dbuf)
  __shared__ unsigned short Vtlds[2][32][72];      //  9 KB (dbuf)

  int tid = threadIdx.x, lane = tid & 63, w = tid >> 6;
  int bh = blockIdx.y, half = blockIdx.z;
  int b = bh >> 3, head = bh & 7;
  int qbase = blockIdx.x * 64 + w * 16;
  int lo = lane & 15, hi = lane >> 4;

  for (int i = tid; i < TI2/4; i += 256)
    ((uint4*)tableL)[i] = ((const uint4*)(tblh + head*TI2))[i];

  bf16x8 qf = *(const bf16x8*)&Q[((size_t)bh*NN + qbase + lo)*DHD + hi*8];
  // u = (ck-cq)*1024 + 1024 = ck*1024 + qoff
  float qoff = fmaf(coord[b*NN + qbase + lo], -(float)TI2*0.5f, (float)TI2*0.5f);

  float m = -1e30f, l = 0.f;
  f32x4 oacc[2];
  oacc[0] = (f32x4){0.f,0.f,0.f,0.f};
  oacc[1] = (f32x4){0.f,0.f,0.f,0.f};
  const float scale2 = 0.17677669529663689f * LOG2E;

  int kt0 = half * (NN/2);
  int sr = tid >> 2, ss = tid & 3;                 // K stage map
  int vr = tid >> 3, vs = tid & 7;                 // V stage map
  {
    *(bf16x8*)&Klds[0][sr][ss*8] =
        *(const bf16x8*)&K[((size_t)bh*NN + kt0 + sr)*DHD + ss*8];
    *(bf16x8*)&Vtlds[0][vr][vs*8] =
        *(const bf16x8*)&Vt[((size_t)bh*DHD + vr)*NN + kt0 + vs*8];
  }
  __syncthreads();

  for (int t = 0; t < 8; ++t) {
    int kt = kt0 + t*64;
    int cur = t & 1;
    // prefetch next K/V tile into registers (hidden under compute)
    bf16x8 kn, vn;
    if (t < 7) {
      kn = *(const bf16x8*)&K[((size_t)bh*NN + kt + 64 + sr)*DHD + ss*8];
      vn = *(const bf16x8*)&Vt[((size_t)bh*DHD + vr)*NN + kt + 64 + vs*8];
    }
    // per-lane coord/mask for this tile's k-slots (L2-hot, 4KB arrays)
    float ck[4][4]; int mk[4][4];
    #pragma unroll
    for (int nt = 0; nt < 4; ++nt) {
      float4 c4 = *(const float4*)&coord[b*NN + kt + nt*16 + hi*4];
      int4   m4 = *(const int4*)  &mask [b*NN + kt + nt*16 + hi*4];
      ck[nt][0] = c4.x; ck[nt][1] = c4.y; ck[nt][2] = c4.z; ck[nt][3] = c4.w;
      mk[nt][0] = m4.x; mk[nt][1] = m4.y; mk[nt][2] = m4.z; mk[nt][3] = m4.w;
    }

    // S^T = K . Q^T
    f32x4 z = {0.f,0.f,0.f,0.f};
    f32x4 sacc[4];
    #pragma unroll
    for (int nt = 0; nt < 4; ++nt) {
      bf16x8 kf = *(const bf16x8*)&Klds[cur][nt*16 + lo][hi*8];
      sacc[nt] = __builtin_amdgcn_mfma_f32_16x16x32_bf16(kf, qf, z, 0, 0, 0);
    }

    // bias lookup + mask (log2 domain)
    float sv[4][4];
    #pragma unroll
    for (int nt = 0; nt < 4; ++nt) {
      #pragma unroll
      for (int r = 0; r < 4; ++r) {
        float u = fmaf(ck[nt][r], (float)TI2*0.5f, qoff);
        u = fminf(fmaxf(u, 0.0f), (float)TI2 - 0.01f);
        int   i0 = (int)u;
        float fr = u - (float)i0;
        unsigned e = tableL[i0];
        __half2 hh = *(__half2*)&e;
        float bias = fmaf(__high2float(hh), fr, __low2float(hh));
        float s = fmaf(sacc[nt][r], scale2, bias);
        sv[nt][r] = mk[nt][r] ? s : -1e31f;
      }
    }

    // lane-local row max (q = lo), then combine across the 4 hi-lanes
    float pm = sv[0][0];
    #pragma unroll
    for (int nt = 0; nt < 4; ++nt)
      #pragma unroll
      for (int r = 0; r < 4; ++r) pm = fmaxf(pm, sv[nt][r]);
    pm = fmaxf(pm, __shfl_xor(pm, 16));
    pm = fmaxf(pm, __shfl_xor(pm, 32));
    float mn = fmaxf(m, pm);
    if (mn > m) {                                  // skip-rescale when no new max
      float sf = __builtin_amdgcn_exp2f(m - mn);
      l *= sf;
      #pragma unroll
      for (int n2 = 0; n2 < 2; ++n2)
        #pragma unroll
        for (int r = 0; r < 4; ++r) oacc[n2][r] *= sf;
      m = mn;
    }

    // P in-register: pack straight into 16x16x16 B-fragments
    bf16x4 pfrag[4];
    #pragma unroll
    for (int nt = 0; nt < 4; ++nt) {
      float p0 = __builtin_amdgcn_exp2f(sv[nt][0] - m);
      float p1 = __builtin_amdgcn_exp2f(sv[nt][1] - m);
      float p2 = __builtin_amdgcn_exp2f(sv[nt][2] - m);
      float p3 = __builtin_amdgcn_exp2f(sv[nt][3] - m);
      l += (p0 + p1) + (p2 + p3);
      union { bf16x4 v; unsigned short u[4]; } pk;
      pk.u[0] = f2bf(p0); pk.u[1] = f2bf(p1);
      pk.u[2] = f2bf(p2); pk.u[3] = f2bf(p3);
      pfrag[nt] = pk.v;
    }

    // O^T += V^T . P^T   (8x 16x16x16 bf16 MFMA, zero cross-lane)
    #pragma unroll
    for (int nt = 0; nt < 4; ++nt) {
      #pragma unroll
      for (int n2 = 0; n2 < 2; ++n2) {
        bf16x4 vf = *(const bf16x4*)&Vtlds[cur][n2*16 + lo][nt*16 + hi*4];
        pv_mfma(oacc[n2], vf, pfrag[nt]);
      }
    }

    // publish next tile, one barrier per iteration
    if (t < 7) {
      *(bf16x8*)&Klds[cur^1][sr][ss*8] = kn;
      *(bf16x8*)&Vtlds[cur^1][vr][vs*8] = vn;
    }
    __syncthreads();
  }

  // epilogue: l across hi-lanes; store unnormalized O^T (bf16) + (m,l)
  l += __shfl_xor(l, 16);
  l += __shfl_xor(l, 32);
  size_t base = ((size_t)(half*BB*NHD + bh)*NN + qbase + lo);
  #pragma unroll
  for (int n2 = 0; n2 < 2; ++n2) {
    union { bf16x4 v; unsigned short u[4]; } ov;
    ov.u[0] = f2bf(oacc[n2][0]); ov.u[1] = f2bf(oacc[n2][1]);
    ov.u[2] = f2bf(oacc[n2][2]); ov.u[3] = f2bf(oacc[n2][3]);
    *(bf16x4*)&pO[base*DHD + n2*16 + hi*4] = ov.v;
  }
  if (hi == 0) pML[base] = make_float2(m, l);
}

// ---- Kernel 4: combine halves + MFMA proj GEMM + bias + residual -----------
__global__ __launch_bounds__(128) void proj_mm_kernel(
    const unsigned short* __restrict__ pO, const float2* __restrict__ pML,
    const unsigned short* __restrict__ Wpt, const float* __restrict__ bp,
    const float* __restrict__ h, float* __restrict__ out)
{
  __shared__ unsigned short alds[32][264];   // merged A-tile (bf16)
  int tid = threadIdx.x;
  int m0 = blockIdx.x * 32, n0 = blockIdx.y * 64;

  // merge the two kv-halves for rows m0..m0+31, all 256 cols
  {
    int r = tid >> 2, q = tid & 3;
    int g = m0 + r, b = g >> 10, n = g & 1023;
    #pragma unroll
    for (int hh = 0; hh < 2; ++hh) {
      int hd = q*2 + hh;
      int bhh = b*NHD + hd;
      float2 ml0 = pML[(size_t)bhh*NN + n];
      float2 ml1 = pML[((size_t)(BB*NHD) + bhh)*NN + n];
      float mm = fmaxf(ml0.x, ml1.x);
      float e0 = __builtin_amdgcn_exp2f(ml0.x - mm);
      float e1 = __builtin_amdgcn_exp2f(ml1.x - mm);
      float inv = 1.0f / fmaf(ml0.y, e0, ml1.y * e1);
      e0 *= inv; e1 *= inv;
      const bf16x8* p0 = (const bf16x8*)&pO[((size_t)bhh*NN + n)*DHD];
      const bf16x8* p1 = (const bf16x8*)&pO[(((size_t)(BB*NHD) + bhh)*NN + n)*DHD];
      #pragma unroll
      for (int j = 0; j < 4; ++j) {
        union { bf16x8 v; unsigned short u[8]; } a, c, o;
        a.v = p0[j]; c.v = p1[j];
        #pragma unroll
        for (int e = 0; e < 8; ++e)
          o.u[e] = f2bf(fmaf(bf2f(a.u[e]), e0, bf2f(c.u[e]) * e1));
        *(bf16x8*)&alds[r][hd*32 + j*8] = o.v;
      }
    }
  }
  __syncthreads();

  // GEMM: 2 waves, wave w -> rows m0+w*16..+15, cols n0..n0+63
  int lane = tid & 63, w = tid >> 6;
  int lo = lane & 15, hi = lane >> 4;
  f32x4 acc[4];
  #pragma unroll
  for (int nt = 0; nt < 4; ++nt) acc[nt] = (f32x4){0.f,0.f,0.f,0.f};

  #pragma unroll
  for (int ks = 0; ks < 8; ++ks) {
    bf16x8 af = *(const bf16x8*)&alds[w*16 + lo][ks*32 + hi*8];
    #pragma unroll
    for (int nt = 0; nt < 4; ++nt) {
      bf16x8 bf = *(const bf16x8*)&Wpt[(size_t)(n0 + nt*16 + lo)*256 + ks*32 + hi*8];
      acc[nt] = __builtin_amdgcn_mfma_f32_16x16x32_bf16(af, bf, acc[nt], 0, 0, 0);
    }
  }

  int m0w = m0 + w*16;
  #pragma unroll
  for (int nt = 0; nt < 4; ++nt) {
    int c = n0 + nt*16 + lo;
    float bpv = bp[c];
    #pragma unroll
    for (int r = 0; r < 4; ++r) {
      size_t o = (size_t)(m0w + hi*4 + r)*HIDD + c;
      out[o] = h[o] + acc[nt][r] + bpv;
    }
  }
}

// ---------------- launch ----------------------------------------------------
extern "C" void kernel_launch(void* const* d_in, const int* in_sizes, int n_in,
                              void* d_out, int out_size, void* d_ws, size_t ws_size,
                              hipStream_t stream)
{
  const float* h     = (const float*)d_in[0];
  const float* coord = (const float*)d_in[1];
  const int*   mask  = (const int*)  d_in[2];
  const float* Wqkv  = (const float*)d_in[3];
  const float* bqkv  = (const float*)d_in[4];
  const float* Wproj = (const float*)d_in[5];
  const float* bproj = (const float*)d_in[6];
  const float* gamma = (const float*)d_in[7];
  const float* beta  = (const float*)d_in[8];
  const float* Wb1   = (const float*)d_in[9];
  const float* bb1   = (const float*)d_in[10];
  const float* Wb2   = (const float*)d_in[11];
  const float* bb2   = (const float*)d_in[12];
  const float* Wb3   = (const float*)d_in[13];
  const float* bb3   = (const float*)d_in[14];
  float* out = (float*)d_out;

  unsigned* tblh = (unsigned*)d_ws;                     // 8*2048 u32 = 64 KB
  float2*   pML  = (float2*)(tblh + NHD*TI2);           // 2*32*1024 f2 = 512 KB
  unsigned short* wtq  = (unsigned short*)(pML + (size_t)2*BB*NHD*NN);
  unsigned short* wtp  = wtq + 768*256;
  unsigned short* qws  = wtp + 256*256;
  unsigned short* kws  = qws + (size_t)BB*NHD*NN*DHD;   // 1 Mi elems each
  unsigned short* vtws = kws + (size_t)BB*NHD*NN*DHD;
  unsigned short* pO   = vtws + (size_t)BB*NHD*NN*DHD;  // 2*32*1024*32 bf16

  prep_kernel<<<dim3(1536), dim3(256), 0, stream>>>(
      Wb1, bb1, Wb2, bb2, Wb3, bb3, Wqkv, Wproj, tblh, wtq, wtp);
  ln_qkv_mm_kernel<<<dim3(BB*NN/64, 6), dim3(256), 0, stream>>>(
      h, gamma, beta, wtq, bqkv, qws, kws, vtws);
  attn_kernel<<<dim3(NN/64, BB*NHD, 2), dim3(256), 0, stream>>>(
      qws, kws, vtws, coord, mask, tblh, pO, pML);
  proj_mm_kernel<<<dim3(BB*NN/32, 4), dim3(128), 0, stream>>>(
      pO, pML, wtp, bproj, h, out);
}

// Round 9
// 73.580 us; speedup vs baseline: 3.2352x; 1.0476x over previous
//
#include <hip/hip_runtime.h>
#include <hip/hip_fp16.h>
#include <math.h>

#define BB   4
#define NN   1024
#define HIDD 256
#define NHD  8
#define DHD  32
#define BHD  64
#define TI2  2048          // table intervals over t in [-1,1]
#define LOG2E 1.4426950408889634f

typedef __attribute__((ext_vector_type(8))) short bf16x8;
typedef __attribute__((ext_vector_type(4))) short bf16x4;
typedef __attribute__((ext_vector_type(4))) float f32x4;

__device__ __forceinline__ unsigned short f2bf(float x) {
  union { float f; unsigned u; } c; c.f = x;
  unsigned r = c.u + 0x7FFFu + ((c.u >> 16) & 1u);
  return (unsigned short)(r >> 16);
}
__device__ __forceinline__ float bf2f(unsigned short b) {
  union { unsigned u; float f; } c; c.u = ((unsigned)b) << 16;
  return c.f;
}

// PV micro-op: oacc += A(V^T frag) . B(P^T frag), 16x16x16 bf16.
__device__ __forceinline__ void pv_mfma(f32x4& acc, bf16x4 a, bf16x4 b) {
#if __has_builtin(__builtin_amdgcn_mfma_f32_16x16x16bf16_1k)
  acc = __builtin_amdgcn_mfma_f32_16x16x16bf16_1k(a, b, acc, 0, 0, 0);
#else
  asm volatile("s_nop 1\n\t"
               "v_mfma_f32_16x16x16_bf16 %0, %1, %2, %0\n\t"
               "s_nop 7\n\t"
               "s_nop 3"
               : "+v"(acc) : "v"(a), "v"(b));
#endif
}

// ---- Kernel 1: prep = bias-table {base,slope} + both weight transposes -----
__global__ __launch_bounds__(256) void prep_kernel(
    const float* __restrict__ Wb1, const float* __restrict__ bb1,
    const float* __restrict__ Wb2, const float* __restrict__ bb2,
    const float* __restrict__ Wb3, const float* __restrict__ bb3,
    const float* __restrict__ Wqkv, const float* __restrict__ Wproj,
    unsigned* __restrict__ tblh, unsigned short* __restrict__ wtq,
    unsigned short* __restrict__ wtp)
{
  __shared__ float h1a[4][64], h1b[4][64], h2a[4][64], h2b[4][64];
  __shared__ float t[16][17];
  int bid = blockIdx.x, tid = threadIdx.x;
  if (bid < 512) {
    int g = tid >> 6, j = tid & 63;
    int pt = bid * 4 + g;
    float t0 = -1.0f + (float)pt     * (2.0f / (float)TI2);
    float t1 = -1.0f + (float)(pt+1) * (2.0f / (float)TI2);
    float w1 = Wb1[j], c1 = bb1[j];
    float z0 = fmaf(t0, w1, c1), z1 = fmaf(t1, w1, c1);
    h1a[g][j] = z0 / (1.0f + __expf(-z0));
    h1b[g][j] = z1 / (1.0f + __expf(-z1));
    __syncthreads();
    float a0 = bb2[j], a1 = a0;
    #pragma unroll 16
    for (int i = 0; i < BHD; ++i) {
      float wv = Wb2[i*BHD + j];
      a0 = fmaf(h1a[g][i], wv, a0);
      a1 = fmaf(h1b[g][i], wv, a1);
    }
    h2a[g][j] = a0 / (1.0f + __expf(-a0));
    h2b[g][j] = a1 / (1.0f + __expf(-a1));
    __syncthreads();
    if (j < NHD) {
      float o0 = bb3[j], o1 = o0;
      #pragma unroll 16
      for (int i = 0; i < BHD; ++i) {
        float wv = Wb3[i*NHD + j];
        o0 = fmaf(h2a[g][i], wv, o0);
        o1 = fmaf(h2b[g][i], wv, o1);
      }
      o0 *= LOG2E; o1 *= LOG2E;
      __half2 hh = __floats2half2_rn(o0, o1 - o0);   // {base, slope}, log2 units
      tblh[j*TI2 + pt] = *(unsigned*)&hh;
    }
  } else {
    const float* W; unsigned short* Wt; int n0, k0, ncols;
    if (bid < 1280) {
      int rb = bid - 512;                 // 768 blocks: 48 x 16
      n0 = (rb % 48) * 16; k0 = (rb / 48) * 16; ncols = 768;
      W = Wqkv; Wt = wtq;
    } else {
      int rc = bid - 1280;                // 256 blocks: 16 x 16
      n0 = (rc & 15) * 16; k0 = (rc >> 4) * 16; ncols = 256;
      W = Wproj; Wt = wtp;
    }
    int sx = tid & 15, sy = tid >> 4;
    t[sy][sx] = W[(size_t)(k0 + sy) * ncols + n0 + sx];
    __syncthreads();
    Wt[(size_t)(n0 + sy) * 256 + k0 + sx] = f2bf(t[sx][sy]);
  }
}

// ---- Kernel 2: fused LayerNorm + MFMA QKV GEMM [4096x256]x[256x768] --------
// Q,K stored [bh][n][d]; V stored TRANSPOSED [bh][d][n] via an LDS block
// transpose (coalesced 128-B global segments instead of 2-B/line scatter).
__global__ __launch_bounds__(256) void ln_qkv_mm_kernel(
    const float* __restrict__ h, const float* __restrict__ gamma,
    const float* __restrict__ beta, const unsigned short* __restrict__ Wt,
    const float* __restrict__ bqkv,
    unsigned short* __restrict__ qws, unsigned short* __restrict__ kws,
    unsigned short* __restrict__ vtws)
{
  __shared__ unsigned short xs[64][260];    // pad 4: row stride 130 dw = 2 mod 32
  int tid = threadIdx.x;
  int m0 = blockIdx.x * 64, n0 = blockIdx.y * 128;

  // --- LN of rows m0..m0+63 into xs (4 threads/row, 64 cols each) ---
  {
    int r = tid >> 2, q = tid & 3;
    const float* hrow = h + (size_t)(m0 + r)*HIDD + q*64;
    float4 xv[16];
    float sum = 0.f, sq = 0.f;
    #pragma unroll
    for (int j = 0; j < 16; ++j) {
      xv[j] = *(const float4*)&hrow[j*4];
      sum += xv[j].x + xv[j].y + xv[j].z + xv[j].w;
      sq  += xv[j].x*xv[j].x + xv[j].y*xv[j].y + xv[j].z*xv[j].z + xv[j].w*xv[j].w;
    }
    sum += __shfl_xor(sum, 1); sq += __shfl_xor(sq, 1);
    sum += __shfl_xor(sum, 2); sq += __shfl_xor(sq, 2);
    float mu  = sum * (1.0f/HIDD);
    float var = sq  * (1.0f/HIDD) - mu*mu;
    float rs  = rsqrtf(var + 1e-5f);
    #pragma unroll
    for (int j2 = 0; j2 < 8; ++j2) {
      union { bf16x8 v; unsigned short u[8]; } o;
      #pragma unroll
      for (int e = 0; e < 2; ++e) {
        float4 x4 = xv[j2*2 + e];
        int col = q*64 + j2*8 + e*4;
        float4 gv = *(const float4*)&gamma[col];
        float4 bv = *(const float4*)&beta[col];
        o.u[e*4+0] = f2bf(fmaf((x4.x - mu)*rs, gv.x, bv.x));
        o.u[e*4+1] = f2bf(fmaf((x4.y - mu)*rs, gv.y, bv.y));
        o.u[e*4+2] = f2bf(fmaf((x4.z - mu)*rs, gv.z, bv.z));
        o.u[e*4+3] = f2bf(fmaf((x4.w - mu)*rs, gv.w, bv.w));
      }
      *(bf16x8*)&xs[r][q*64 + j2*8] = o.v;
    }
  }
  __syncthreads();

  // --- GEMM: wave w -> rows m0+w*16..+15, cols n0..n0+127 ---
  int lane = tid & 63, w = tid >> 6;
  int lo = lane & 15, hi = lane >> 4;
  int m0w = m0 + w*16;
  f32x4 acc[8];
  #pragma unroll
  for (int nt = 0; nt < 8; ++nt) acc[nt] = (f32x4){0.f,0.f,0.f,0.f};

  #pragma unroll
  for (int ks = 0; ks < 8; ++ks) {
    bf16x8 af = *(const bf16x8*)&xs[w*16 + lo][ks*32 + hi*8];
    #pragma unroll
    for (int nt = 0; nt < 8; ++nt) {
      bf16x8 bf = *(const bf16x8*)&Wt[(size_t)(n0 + nt*16 + lo)*256 + ks*32 + hi*8];
      acc[nt] = __builtin_amdgcn_mfma_f32_16x16x32_bf16(af, bf, acc[nt], 0, 0, 0);
    }
  }

  int b = m0w >> 10;
  if (n0 < 512) {
    // Q or K (block-uniform): direct scatter [bh][n][d]
    unsigned short* dst = (n0 < 256) ? qws : kws;
    int nbase = (m0w & 1023) + hi*4;
    #pragma unroll
    for (int nt = 0; nt < 8; ++nt) {
      int c = n0 + nt*16 + lo;
      int cr = c & 255;
      int head = cr >> 5, d = cr & 31;
      float bq = bqkv[c];
      size_t bh = (size_t)(b*NHD + head);
      #pragma unroll
      for (int r = 0; r < 4; ++r)
        dst[(bh*NN + nbase + r)*DHD + d] = f2bf(acc[nt][r] + bq);
    }
  } else {
    // V: transpose through LDS (reuse xs), then coalesced [bh][d][n] store
    __syncthreads();                      // all waves done reading xs
    unsigned short (*vt)[72] = (unsigned short(*)[72])&xs[0][0];  // [128][72]
    #pragma unroll
    for (int nt = 0; nt < 8; ++nt) {
      int cr = nt*16 + lo;                // block-local col 0..127
      float bq = bqkv[n0 + cr];
      union { unsigned short u[4]; unsigned wd[2]; } pk;
      #pragma unroll
      for (int r = 0; r < 4; ++r) pk.u[r] = f2bf(acc[nt][r] + bq);
      int col = w*16 + hi*4;              // n within 0..63
      *(unsigned*)&vt[cr][col]     = pk.wd[0];
      *(unsigned*)&vt[cr][col + 2] = pk.wd[1];
    }
    __syncthreads();
    int nn0 = m0 & 1023;
    #pragma unroll
    for (int i = 0; i < 4; ++i) {
      int u = i*256 + tid;
      int row = u >> 3, ch = u & 7;       // row 0..127, 8-short chunk 0..7
      int cr256 = (n0 - 512) + row;
      int head = cr256 >> 5, d = cr256 & 31;
      *(bf16x8*)&vtws[((size_t)(b*NHD + head)*DHD + d)*NN + nn0 + ch*8] =
          *(const bf16x8*)&vt[row][ch*8];
    }
  }
}

// ------- Kernel 3: swapped-operand MFMA flash attention (r7 verbatim) -------
// S^T = mfma(K,Q): lane owns q=lane&15, k=hi*4+r (+16nt). Softmax lane-local.
// P stays in registers: S^T D-layout == B-frag layout of 16x16x16 bf16 MFMA
// => O^T = V^T . P^T with no cross-lane traffic.
__global__ __launch_bounds__(256, 4) void attn_kernel(
    const unsigned short* __restrict__ Q, const unsigned short* __restrict__ K,
    const unsigned short* __restrict__ Vt, const float* __restrict__ coord,
    const int* __restrict__ mask, const unsigned* __restrict__ tblh,
    unsigned short* __restrict__ pO, float2* __restrict__ pML)
{
  __shared__ unsigned tableL[TI2];                 // 8 KB (half2, log2 units)
  __shared__ unsigned short Klds[2][64][40];       // 10 KB (dbuf)
  __shared__ unsigned short Vtlds[2][32][72];      //  9 KB (dbuf)

  int tid = threadIdx.x, lane = tid & 63, w = tid >> 6;
  int bh = blockIdx.y, half = blockIdx.z;
  int b = bh >> 3, head = bh & 7;
  int qbase = blockIdx.x * 64 + w * 16;
  int lo = lane & 15, hi = lane >> 4;

  for (int i = tid; i < TI2/4; i += 256)
    ((uint4*)tableL)[i] = ((const uint4*)(tblh + head*TI2))[i];

  bf16x8 qf = *(const bf16x8*)&Q[((size_t)bh*NN + qbase + lo)*DHD + hi*8];
  // u = (ck-cq)*1024 + 1024 = ck*1024 + qoff
  float qoff = fmaf(coord[b*NN + qbase + lo], -(float)TI2*0.5f, (float)TI2*0.5f);

  float m = -1e30f, l = 0.f;
  f32x4 oacc[2];
  oacc[0] = (f32x4){0.f,0.f,0.f,0.f};
  oacc[1] = (f32x4){0.f,0.f,0.f,0.f};
  const float scale2 = 0.17677669529663689f * LOG2E;

  int kt0 = half * (NN/2);
  int sr = tid >> 2, ss = tid & 3;                 // K stage map
  int vr = tid >> 3, vs = tid & 7;                 // V stage map
  {
    *(bf16x8*)&Klds[0][sr][ss*8] =
        *(const bf16x8*)&K[((size_t)bh*NN + kt0 + sr)*DHD + ss*8];
    *(bf16x8*)&Vtlds[0][vr][vs*8] =
        *(const bf16x8*)&Vt[((size_t)bh*DHD + vr)*NN + kt0 + vs*8];
  }
  __syncthreads();

  for (int t = 0; t < 8; ++t) {
    int kt = kt0 + t*64;
    int cur = t & 1;
    // prefetch next K/V tile into registers (hidden under compute)
    bf16x8 kn, vn;
    if (t < 7) {
      kn = *(const bf16x8*)&K[((size_t)bh*NN + kt + 64 + sr)*DHD + ss*8];
      vn = *(const bf16x8*)&Vt[((size_t)bh*DHD + vr)*NN + kt + 64 + vs*8];
    }
    // per-lane coord/mask for this tile's k-slots (L2-hot, 4KB arrays)
    float ck[4][4]; int mk[4][4];
    #pragma unroll
    for (int nt = 0; nt < 4; ++nt) {
      float4 c4 = *(const float4*)&coord[b*NN + kt + nt*16 + hi*4];
      int4   m4 = *(const int4*)  &mask [b*NN + kt + nt*16 + hi*4];
      ck[nt][0] = c4.x; ck[nt][1] = c4.y; ck[nt][2] = c4.z; ck[nt][3] = c4.w;
      mk[nt][0] = m4.x; mk[nt][1] = m4.y; mk[nt][2] = m4.z; mk[nt][3] = m4.w;
    }

    // S^T = K . Q^T
    f32x4 z = {0.f,0.f,0.f,0.f};
    f32x4 sacc[4];
    #pragma unroll
    for (int nt = 0; nt < 4; ++nt) {
      bf16x8 kf = *(const bf16x8*)&Klds[cur][nt*16 + lo][hi*8];
      sacc[nt] = __builtin_amdgcn_mfma_f32_16x16x32_bf16(kf, qf, z, 0, 0, 0);
    }

    // bias lookup + mask (log2 domain)
    float sv[4][4];
    #pragma unroll
    for (int nt = 0; nt < 4; ++nt) {
      #pragma unroll
      for (int r = 0; r < 4; ++r) {
        float u = fmaf(ck[nt][r], (float)TI2*0.5f, qoff);
        u = fminf(fmaxf(u, 0.0f), (float)TI2 - 0.01f);
        int   i0 = (int)u;
        float fr = u - (float)i0;
        unsigned e = tableL[i0];
        __half2 hh = *(__half2*)&e;
        float bias = fmaf(__high2float(hh), fr, __low2float(hh));
        float s = fmaf(sacc[nt][r], scale2, bias);
        sv[nt][r] = mk[nt][r] ? s : -1e31f;
      }
    }

    // lane-local row max (q = lo), then combine across the 4 hi-lanes
    float pm = sv[0][0];
    #pragma unroll
    for (int nt = 0; nt < 4; ++nt)
      #pragma unroll
      for (int r = 0; r < 4; ++r) pm = fmaxf(pm, sv[nt][r]);
    pm = fmaxf(pm, __shfl_xor(pm, 16));
    pm = fmaxf(pm, __shfl_xor(pm, 32));
    float mn = fmaxf(m, pm);
    if (mn > m) {                                  // skip-rescale when no new max
      float sf = __builtin_amdgcn_exp2f(m - mn);
      l *= sf;
      #pragma unroll
      for (int n2 = 0; n2 < 2; ++n2)
        #pragma unroll
        for (int r = 0; r < 4; ++r) oacc[n2][r] *= sf;
      m = mn;
    }

    // P in-register: pack straight into 16x16x16 B-fragments
    bf16x4 pfrag[4];
    #pragma unroll
    for (int nt = 0; nt < 4; ++nt) {
      float p0 = __builtin_amdgcn_exp2f(sv[nt][0] - m);
      float p1 = __builtin_amdgcn_exp2f(sv[nt][1] - m);
      float p2 = __builtin_amdgcn_exp2f(sv[nt][2] - m);
      float p3 = __builtin_amdgcn_exp2f(sv[nt][3] - m);
      l += (p0 + p1) + (p2 + p3);
      union { bf16x4 v; unsigned short u[4]; } pk;
      pk.u[0] = f2bf(p0); pk.u[1] = f2bf(p1);
      pk.u[2] = f2bf(p2); pk.u[3] = f2bf(p3);
      pfrag[nt] = pk.v;
    }

    // O^T += V^T . P^T   (8x 16x16x16 bf16 MFMA, zero cross-lane)
    #pragma unroll
    for (int nt = 0; nt < 4; ++nt) {
      #pragma unroll
      for (int n2 = 0; n2 < 2; ++n2) {
        bf16x4 vf = *(const bf16x4*)&Vtlds[cur][n2*16 + lo][nt*16 + hi*4];
        pv_mfma(oacc[n2], vf, pfrag[nt]);
      }
    }

    // publish next tile, one barrier per iteration
    if (t < 7) {
      *(bf16x8*)&Klds[cur^1][sr][ss*8] = kn;
      *(bf16x8*)&Vtlds[cur^1][vr][vs*8] = vn;
    }
    __syncthreads();
  }

  // epilogue: l across hi-lanes; store unnormalized O^T (bf16) + (m,l)
  l += __shfl_xor(l, 16);
  l += __shfl_xor(l, 32);
  size_t base = ((size_t)(half*BB*NHD + bh)*NN + qbase + lo);
  #pragma unroll
  for (int n2 = 0; n2 < 2; ++n2) {
    union { bf16x4 v; unsigned short u[4]; } ov;
    ov.u[0] = f2bf(oacc[n2][0]); ov.u[1] = f2bf(oacc[n2][1]);
    ov.u[2] = f2bf(oacc[n2][2]); ov.u[3] = f2bf(oacc[n2][3]);
    *(bf16x4*)&pO[base*DHD + n2*16 + hi*4] = ov.v;
  }
  if (hi == 0) pML[base] = make_float2(m, l);
}

// ---- Kernel 4: combine halves + MFMA proj GEMM + bias + residual -----------
__global__ __launch_bounds__(128) void proj_mm_kernel(
    const unsigned short* __restrict__ pO, const float2* __restrict__ pML,
    const unsigned short* __restrict__ Wpt, const float* __restrict__ bp,
    const float* __restrict__ h, float* __restrict__ out)
{
  __shared__ unsigned short alds[32][264];   // merged A-tile (bf16)
  int tid = threadIdx.x;
  int m0 = blockIdx.x * 32, n0 = blockIdx.y * 64;

  // merge the two kv-halves for rows m0..m0+31, all 256 cols
  {
    int r = tid >> 2, q = tid & 3;
    int g = m0 + r, b = g >> 10, n = g & 1023;
    #pragma unroll
    for (int hh = 0; hh < 2; ++hh) {
      int hd = q*2 + hh;
      int bhh = b*NHD + hd;
      float2 ml0 = pML[(size_t)bhh*NN + n];
      float2 ml1 = pML[((size_t)(BB*NHD) + bhh)*NN + n];
      float mm = fmaxf(ml0.x, ml1.x);
      float e0 = __builtin_amdgcn_exp2f(ml0.x - mm);
      float e1 = __builtin_amdgcn_exp2f(ml1.x - mm);
      float inv = 1.0f / fmaf(ml0.y, e0, ml1.y * e1);
      e0 *= inv; e1 *= inv;
      const bf16x8* p0 = (const bf16x8*)&pO[((size_t)bhh*NN + n)*DHD];
      const bf16x8* p1 = (const bf16x8*)&pO[(((size_t)(BB*NHD) + bhh)*NN + n)*DHD];
      #pragma unroll
      for (int j = 0; j < 4; ++j) {
        union { bf16x8 v; unsigned short u[8]; } a, c, o;
        a.v = p0[j]; c.v = p1[j];
        #pragma unroll
        for (int e = 0; e < 8; ++e)
          o.u[e] = f2bf(fmaf(bf2f(a.u[e]), e0, bf2f(c.u[e]) * e1));
        *(bf16x8*)&alds[r][hd*32 + j*8] = o.v;
      }
    }
  }
  __syncthreads();

  // GEMM: 2 waves, wave w -> rows m0+w*16..+15, cols n0..n0+63
  int lane = tid & 63, w = tid >> 6;
  int lo = lane & 15, hi = lane >> 4;
  f32x4 acc[4];
  #pragma unroll
  for (int nt = 0; nt < 4; ++nt) acc[nt] = (f32x4){0.f,0.f,0.f,0.f};

  #pragma unroll
  for (int ks = 0; ks < 8; ++ks) {
    bf16x8 af = *(const bf16x8*)&alds[w*16 + lo][ks*32 + hi*8];
    #pragma unroll
    for (int nt = 0; nt < 4; ++nt) {
      bf16x8 bf = *(const bf16x8*)&Wpt[(size_t)(n0 + nt*16 + lo)*256 + ks*32 + hi*8];
      acc[nt] = __builtin_amdgcn_mfma_f32_16x16x32_bf16(af, bf, acc[nt], 0, 0, 0);
    }
  }

  int m0w = m0 + w*16;
  #pragma unroll
  for (int nt = 0; nt < 4; ++nt) {
    int c = n0 + nt*16 + lo;
    float bpv = bp[c];
    #pragma unroll
    for (int r = 0; r < 4; ++r) {
      size_t o = (size_t)(m0w + hi*4 + r)*HIDD + c;
      out[o] = h[o] + acc[nt][r] + bpv;
    }
  }
}

// ---------------- launch ----------------------------------------------------
extern "C" void kernel_launch(void* const* d_in, const int* in_sizes, int n_in,
                              void* d_out, int out_size, void* d_ws, size_t ws_size,
                              hipStream_t stream)
{
  const float* h     = (const float*)d_in[0];
  const float* coord = (const float*)d_in[1];
  const int*   mask  = (const int*)  d_in[2];
  const float* Wqkv  = (const float*)d_in[3];
  const float* bqkv  = (const float*)d_in[4];
  const float* Wproj = (const float*)d_in[5];
  const float* bproj = (const float*)d_in[6];
  const float* gamma = (const float*)d_in[7];
  const float* beta  = (const float*)d_in[8];
  const float* Wb1   = (const float*)d_in[9];
  const float* bb1   = (const float*)d_in[10];
  const float* Wb2   = (const float*)d_in[11];
  const float* bb2   = (const float*)d_in[12];
  const float* Wb3   = (const float*)d_in[13];
  const float* bb3   = (const float*)d_in[14];
  float* out = (float*)d_out;

  unsigned* tblh = (unsigned*)d_ws;                     // 8*2048 u32 = 64 KB
  float2*   pML  = (float2*)(tblh + NHD*TI2);           // 2*32*1024 f2 = 512 KB
  unsigned short* wtq  = (unsigned short*)(pML + (size_t)2*BB*NHD*NN);
  unsigned short* wtp  = wtq + 768*256;
  unsigned short* qws  = wtp + 256*256;
  unsigned short* kws  = qws + (size_t)BB*NHD*NN*DHD;   // 1 Mi elems each
  unsigned short* vtws = kws + (size_t)BB*NHD*NN*DHD;
  unsigned short* pO   = vtws + (size_t)BB*NHD*NN*DHD;  // 2*32*1024*32 bf16

  prep_kernel<<<dim3(1536), dim3(256), 0, stream>>>(
      Wb1, bb1, Wb2, bb2, Wb3, bb3, Wqkv, Wproj, tblh, wtq, wtp);
  ln_qkv_mm_kernel<<<dim3(BB*NN/64, 6), dim3(256), 0, stream>>>(
      h, gamma, beta, wtq, bqkv, qws, kws, vtws);
  attn_kernel<<<dim3(NN/64, BB*NHD, 2), dim3(256), 0, stream>>>(
      qws, kws, vtws, coord, mask, tblh, pO, pML);
  proj_mm_kernel<<<dim3(BB*NN/32, 4), dim3(128), 0, stream>>>(
      pO, pML, wtp, bproj, h, out);
}